// Round 15
// baseline (147.099 us; speedup 1.0000x reference)
//
#include <hip/hip_runtime.h>
#include <math.h>

#define BB_ 8
#define CC_ 256
#define HWSZ 4096            // 64*64
#define CHW (CC_*HWSZ)       // 1,048,576
#define BCHW (BB_*CHW)       // 8,388,608

typedef __attribute__((ext_vector_type(8))) short short8v;
typedef __attribute__((ext_vector_type(4))) float f32x4;

struct Taps5 { float t[5]; };

__device__ inline ushort f2b(float f){
    uint u = __float_as_uint(f);
    u += 0x7FFF + ((u >> 16) & 1);
    return (ushort)(u >> 16);
}
__device__ inline float b2f(ushort u){
    return __uint_as_float(((uint)u) << 16);
}
__device__ inline ushort f2h(float f){
    _Float16 h = (_Float16)f; ushort u; __builtin_memcpy(&u, &h, 2); return u;
}
__device__ inline float h2f(ushort u){
    _Float16 h; __builtin_memcpy(&h, &u, 2); return (float)h;
}
// fast exp: exp(x) = 2^(x*log2e) via native v_exp_f32
__device__ __forceinline__ float fexp(float x){
    return __builtin_amdgcn_exp2f(x * 1.44269504088896340736f);
}
// async 16B global -> LDS (linear dest = wave-uniform base + lane*16)
__device__ __forceinline__ void gload16(const ushort* g, ushort* l){
    __builtin_amdgcn_global_load_lds(
        (const __attribute__((address_space(1))) void*)g,
        (__attribute__((address_space(3))) void*)l, 16, 0, 0);
}

// ================= K1: mega prep, role-INTERLEAVED (prepx | plane6 alternating, prepw tail) =================
__global__ __launch_bounds__(256) void prep_all(const float* __restrict__ x,
        const float* __restrict__ Wk, const float* __restrict__ Wq,
        const float* __restrict__ Wr, const float* __restrict__ Wv,
        const float* __restrict__ bv, const float* __restrict__ br,
        ushort* __restrict__ xb, ushort* __restrict__ xTb,
        ushort* __restrict__ P, ushort* __restrict__ S1, ushort* __restrict__ S2,
        ushort* __restrict__ Wkb, ushort* __restrict__ Wqb,
        float* __restrict__ brc, float* __restrict__ Wrv,
        Taps5 t3, Taps5 t5){
    __shared__ float smem[64*65];
    const int bid0 = blockIdx.x;
    // interleave: even -> prepx[bid0>>1], odd -> plane[bid0>>1]; >=4096 -> prepw
    const int bid = (bid0 < 4096) ? ((bid0 & 1) ? 2048 + (bid0 >> 1) : (bid0 >> 1)) : bid0;
    const int tid = threadIdx.x;

    if (bid < 2048){
        // ---- prepx role ----
        const int b = bid >> 8, c0 = ((bid >> 6) & 3)*64, h0 = (bid & 63)*64;
        const float* xp = x + (size_t)b*CHW;
        float (*T)[65] = (float(*)[65])smem;
        const int cl = tid >> 4;
        const int hl = (tid & 15) * 4;
        #pragma unroll
        for (int p = 0; p < 4; ++p){
            int c = c0 + p*16 + cl;
            float4 v = *(const float4*)&xp[(size_t)c*4096 + h0 + hl];
            ushort4 u; u.x = f2b(v.x); u.y = f2b(v.y); u.z = f2b(v.z); u.w = f2b(v.w);
            *(ushort4*)&xb[(size_t)b*CHW + (size_t)c*4096 + h0 + hl] = u;
            T[p*16+cl][hl+0] = v.x;
            T[p*16+cl][hl+1] = v.y;
            T[p*16+cl][hl+2] = v.z;
            T[p*16+cl][hl+3] = v.w;
        }
        __syncthreads();
        const int hr = tid >> 2;
        const int cs = (tid & 3) * 16;
        short8v o0, o1;
        #pragma unroll
        for (int i = 0; i < 8; ++i) o0[i] = (short)f2b(T[cs+i][hr]);
        #pragma unroll
        for (int i = 0; i < 8; ++i) o1[i] = (short)f2b(T[cs+8+i][hr]);
        ushort* dst = xTb + (size_t)b*CHW + (size_t)(h0+hr)*256 + c0 + cs;
        *(short8v*)dst = o0;
        *(short8v*)(dst+8) = o1;
        return;
    }
    if (bid < 4096){
        // ---- plane6 role ----
        const size_t base = (size_t)(bid - 2048) * HWSZ;
        const int c = tid & 63, rb = tid >> 6;
        float* bndA = smem;
        float* bndB = smem + 512;
        float* red  = smem + 1536;
        float v[16];
        #pragma unroll
        for (int i = 0; i < 16; ++i) v[i] = x[base + (rb*16 + i)*64 + c];
        float h3[16];
        #pragma unroll
        for (int i = 0; i < 16; ++i){
            float l = __shfl(v[i], c-1, 64); l = (c > 0)  ? l : 0.f;
            float r = __shfl(v[i], c+1, 64); r = (c < 63) ? r : 0.f;
            h3[i] = t3.t[0]*l + t3.t[1]*v[i] + t3.t[2]*r;
        }
        bndA[(rb*2+0)*64 + c] = h3[0]; bndA[(rb*2+1)*64 + c] = h3[15];
        __syncthreads();
        const float upA = (rb > 0) ? bndA[((rb-1)*2+1)*64 + c] : 0.f;
        const float dnA = (rb < 3) ? bndA[((rb+1)*2+0)*64 + c] : 0.f;
        float g1[16];
        #pragma unroll
        for (int i = 0; i < 16; ++i){
            float a = (i > 0)  ? h3[i-1] : upA;
            float b = (i < 15) ? h3[i+1] : dnA;
            g1[i] = t3.t[0]*a + t3.t[1]*h3[i] + t3.t[2]*b;
        }
        #pragma unroll
        for (int i = 0; i < 16; ++i){
            float m2 = __shfl(g1[i], c-2, 64); m2 = (c > 1)  ? m2 : 0.f;
            float m1 = __shfl(g1[i], c-1, 64); m1 = (c > 0)  ? m1 : 0.f;
            float p1 = __shfl(g1[i], c+1, 64); p1 = (c < 63) ? p1 : 0.f;
            float p2 = __shfl(g1[i], c+2, 64); p2 = (c < 62) ? p2 : 0.f;
            h3[i] = t5.t[0]*m2 + t5.t[1]*m1 + t5.t[2]*g1[i] + t5.t[3]*p1 + t5.t[4]*p2;
        }
        bndB[(rb*4+0)*64 + c] = h3[0];  bndB[(rb*4+1)*64 + c] = h3[1];
        bndB[(rb*4+2)*64 + c] = h3[14]; bndB[(rb*4+3)*64 + c] = h3[15];
        __syncthreads();
        const float u2 = (rb > 0) ? bndB[((rb-1)*4+2)*64 + c] : 0.f;
        const float u1 = (rb > 0) ? bndB[((rb-1)*4+3)*64 + c] : 0.f;
        const float d1 = (rb < 3) ? bndB[((rb+1)*4+0)*64 + c] : 0.f;
        const float d2 = (rb < 3) ? bndB[((rb+1)*4+1)*64 + c] : 0.f;
        float g2[16];
        #pragma unroll
        for (int i = 0; i < 16; ++i){
            float a = (i >= 2) ? h3[i-2] : (i == 1 ? u1 : u2);
            float b = (i >= 1) ? h3[i-1] : u1;
            float d = (i < 15) ? h3[i+1] : d1;
            float e = (i < 14) ? h3[i+2] : (i == 14 ? d1 : d2);
            g2[i] = t5.t[0]*a + t5.t[1]*b + t5.t[2]*h3[i] + t5.t[3]*d + t5.t[4]*e;
        }
        const size_t orow = base + (size_t)rb*16*64 + c;
        #pragma unroll
        for (int i = 0; i < 16; ++i){
            S1[orow + i*64] = f2b(v[i] - g1[i]);
            S2[orow + i*64] = f2b(g1[i] - g2[i]);
        }
        const int wid = tid >> 6, lane = tid & 63;
        #pragma unroll
        for (int g = 0; g < 3; ++g){
            float val[16];
            #pragma unroll
            for (int i = 0; i < 16; ++i)
                val[i] = (g == 0) ? v[i] : (g == 1 ? v[i] - g1[i] : g1[i] - g2[i]);
            float mx = val[0];
            #pragma unroll
            for (int i = 1; i < 16; ++i) mx = fmaxf(mx, val[i]);
            #pragma unroll
            for (int off = 32; off > 0; off >>= 1) mx = fmaxf(mx, __shfl_xor(mx, off));
            if (lane == 0) red[g*8 + wid] = mx;
            __syncthreads();
            mx = fmaxf(fmaxf(red[g*8+0], red[g*8+1]), fmaxf(red[g*8+2], red[g*8+3]));
            float s = 0.f;
            #pragma unroll
            for (int i = 0; i < 16; ++i){ val[i] = fexp(val[i] - mx); s += val[i]; }
            #pragma unroll
            for (int off = 32; off > 0; off >>= 1) s += __shfl_xor(s, off);
            if (lane == 0) red[g*8 + 4 + wid] = s;
            __syncthreads();
            s = red[g*8+4] + red[g*8+5] + red[g*8+6] + red[g*8+7];
            float inv = 1.f / s;
            ushort* Pg = P + (size_t)g*BCHW;
            #pragma unroll
            for (int i = 0; i < 16; ++i) Pg[orow + i*64] = f2b(val[i]*inv);
        }
        return;
    }
    // ---- prepw role ----
    const int blk = bid - 4096;
    if (blk < 128){
        const float* src = (blk < 64) ? Wk : Wq;
        ushort* dst = (blk < 64) ? Wkb : Wqb;
        int i = (blk & 63)*256 + tid;
        float4 v = *(const float4*)&src[i*4];
        ushort4 u; u.x = f2b(v.x); u.y = f2b(v.y); u.z = f2b(v.z); u.w = f2b(v.w);
        *(ushort4*)&dst[i*4] = u;
        return;
    }
    if (blk < 144){
        int m = (blk - 128)*16 + (tid >> 4);
        int l16 = tid & 15;
        float s = 0.f;
        #pragma unroll
        for (int t = 0; t < 4; ++t){
            float4 a = *(const float4*)&Wr[(size_t)m*256 + l16*16 + t*4];
            float4 b = *(const float4*)&bv[l16*16 + t*4];
            s += a.x*b.x + a.y*b.y + a.z*b.z + a.w*b.w;
        }
        #pragma unroll
        for (int off = 1; off < 16; off <<= 1) s += __shfl_xor(s, off);
        if (l16 == 0) brc[m] = br[m] + s;
        return;
    }
    {
        const int t = blk - 144;
        const int m0 = (t >> 2) * 64, n0 = (t & 3) * 64;
        float* As = smem;
        float* Bs = smem + 2112;
        const int tx = tid & 15, ty = tid >> 4;
        float acc[4][4] = {};
        for (int k0 = 0; k0 < 256; k0 += 32){
            int kk = tid & 31, ml = tid >> 5;
            #pragma unroll
            for (int r = 0; r < 8; ++r){
                int m = ml + r*8;
                As[kk*66 + m] = Wr[(size_t)(m0+m)*256 + k0 + kk];
            }
            int j = tid & 63, kg = tid >> 6;
            #pragma unroll
            for (int r = 0; r < 8; ++r){
                int kk2 = kg + r*4;
                Bs[kk2*64 + j] = Wv[(size_t)(k0+kk2)*256 + n0 + j];
            }
            __syncthreads();
            #pragma unroll
            for (int kk2 = 0; kk2 < 32; ++kk2){
                float4 bv4 = *(const float4*)&Bs[kk2*64 + tx*4];
                float av[4] = {As[kk2*66+ty*4+0], As[kk2*66+ty*4+1], As[kk2*66+ty*4+2], As[kk2*66+ty*4+3]};
                float bw[4] = {bv4.x, bv4.y, bv4.z, bv4.w};
                #pragma unroll
                for (int i = 0; i < 4; ++i)
                    #pragma unroll
                    for (int j2 = 0; j2 < 4; ++j2)
                        acc[i][j2] += av[i]*bw[j2];
            }
            __syncthreads();
        }
        #pragma unroll
        for (int i = 0; i < 4; ++i){
            float4 wv4 = {acc[i][0], acc[i][1], acc[i][2], acc[i][3]};
            *(float4*)&Wrv[(size_t)(m0+ty*4+i)*256 + n0 + tx*4] = wv4;
        }
    }
}

// ================= K2: kq2 — keys GEMM (512) + qpre GEMM (512), uniform body =================
__global__ __launch_bounds__(256) void kq2_kernel(const ushort* __restrict__ Wkb,
        const ushort* __restrict__ xTb, const ushort* __restrict__ Wqb,
        const float* __restrict__ bk, const float* __restrict__ bq,
        ushort* __restrict__ FreH, ushort* __restrict__ qpreH){
    __shared__ ushort As[128*64];
    __shared__ ushort Bs[128*64];
    const int bid = blockIdx.x;
    const int vid = (bid & 7)*128 + (bid >> 3);   // 1024 blocks, bijective
    const int tid = threadIdx.x;
    const int l = tid & 63, w = tid >> 6;
    const int wm = (w >> 1) * 64, wn = (w & 1) * 64;
    const int lr8 = l >> 3;
    const int lk = ((l & 7) ^ lr8) << 3;
    const bool keys = (vid < 512);
    const int sub = keys ? vid : vid - 512;
    const int b = sub >> 6;
    const int t = sub & 63;
    const int m0 = keys ? (t & 1)*128 : (t >> 1)*128;
    const int n0 = keys ? (t >> 1)*128 : (t & 1)*128;
    const ushort* Ag = keys
        ? Wkb + (size_t)(m0 + w*32 + lr8)*256 + lk
        : xTb + (size_t)b*CHW + (size_t)(m0 + w*32 + lr8)*256 + lk;
    const ushort* Bg = keys
        ? xTb + (size_t)b*CHW + (size_t)(n0 + w*32 + lr8)*256 + lk
        : Wqb + (size_t)(n0 + w*32 + lr8)*256 + lk;
    int rabase[4], raswz[4], rbbase[4], rbswz[4];
    #pragma unroll
    for (int f = 0; f < 4; ++f){
        int ra = wm + f*16 + (l & 15);
        int rb = wn + f*16 + (l & 15);
        rabase[f] = ra*64 + (l>>4)*8;  raswz[f] = (ra & 7) << 3;
        rbbase[f] = rb*64 + (l>>4)*8;  rbswz[f] = (rb & 7) << 3;
    }
    f32x4 acc[4][4] = {};
    for (int kt = 0; kt < 4; ++kt){
        #pragma unroll
        for (int i = 0; i < 4; ++i){
            gload16(Ag + (size_t)i*8*256 + kt*64, &As[(w*32 + i*8)*64]);
            gload16(Bg + (size_t)i*8*256 + kt*64, &Bs[(w*32 + i*8)*64]);
        }
        __syncthreads();
        #pragma unroll
        for (int ks = 0; ks < 2; ++ks){
            short8v af[4], bf[4];
            #pragma unroll
            for (int f = 0; f < 4; ++f){
                af[f] = *(const short8v*)&As[(rabase[f] + ks*32) ^ raswz[f]];
                bf[f] = *(const short8v*)&Bs[(rbbase[f] + ks*32) ^ rbswz[f]];
            }
            #pragma unroll
            for (int fi = 0; fi < 4; ++fi)
                #pragma unroll
                for (int fj = 0; fj < 4; ++fj)
                    acc[fi][fj] = __builtin_amdgcn_mfma_f32_16x16x32_bf16(af[fi], bf[fj], acc[fi][fj], 0, 0, 0);
        }
        __syncthreads();
    }
    const int erow = (l >> 4) * 4, ecol = l & 15;
    if (keys){
        #pragma unroll
        for (int fi = 0; fi < 4; ++fi){
            #pragma unroll
            for (int r = 0; r < 4; ++r){
                const int m = m0 + wm + fi*16 + erow + r;
                const float madd = bk[m];
                #pragma unroll
                for (int fj = 0; fj < 4; ++fj){
                    const int n = n0 + wn + fj*16 + ecol;
                    FreH[(size_t)b*CHW + (size_t)m*4096 + n] = f2h(acc[fi][fj][r] + madd);
                }
            }
        }
    } else {
        #pragma unroll
        for (int fi = 0; fi < 4; ++fi){
            #pragma unroll
            for (int r = 0; r < 4; ++r){
                const int m = m0 + wm + fi*16 + erow + r;
                #pragma unroll
                for (int fj = 0; fj < 4; ++fj){
                    const int n = n0 + wn + fj*16 + ecol;
                    qpreH[(size_t)b*CHW + (size_t)m*256 + n] = f2h(acc[fi][fj][r] + bq[n]);
                }
            }
        }
    }
}

// ================= K3: sm2 — keys rowsm over 4096 (bid<2048) + q softmax over 256 =================
__global__ __launch_bounds__(256) void sm2_kernel(const ushort* __restrict__ FreH,
        const ushort* __restrict__ qpreH,
        ushort* __restrict__ keysb, ushort* __restrict__ qTb){
    const int bid = blockIdx.x;
    const int tid = threadIdx.x;
    if (bid < 2048){
        const size_t base = (size_t)bid * HWSZ + tid * 16;
        float v[16];
        {
            short8v a = *(const short8v*)(FreH + base);
            short8v b = *(const short8v*)(FreH + base + 8);
            #pragma unroll
            for (int i = 0; i < 8; ++i){ v[i] = h2f((ushort)a[i]); v[8+i] = h2f((ushort)b[i]); }
        }
        float m = v[0];
        #pragma unroll
        for (int i = 1; i < 16; ++i) m = fmaxf(m, v[i]);
        #pragma unroll
        for (int off = 32; off > 0; off >>= 1) m = fmaxf(m, __shfl_xor(m, off));
        __shared__ float redm[4], reds[4];
        int wid = tid >> 6, lane = tid & 63;
        if (lane == 0) redm[wid] = m;
        __syncthreads();
        m = fmaxf(fmaxf(redm[0], redm[1]), fmaxf(redm[2], redm[3]));
        float s = 0.f;
        #pragma unroll
        for (int i = 0; i < 16; ++i){ v[i] = fexp(v[i] - m); s += v[i]; }
        #pragma unroll
        for (int off = 32; off > 0; off >>= 1) s += __shfl_xor(s, off);
        if (lane == 0) reds[wid] = s;
        __syncthreads();
        s = reds[0] + reds[1] + reds[2] + reds[3];
        float inv = 1.f / s;
        short8v o0, o1;
        #pragma unroll
        for (int i = 0; i < 8; ++i){ o0[i] = (short)f2b(v[i]*inv); o1[i] = (short)f2b(v[8+i]*inv); }
        ushort* op = keysb + base;
        *(short8v*)op = o0; *(short8v*)(op+8) = o1;
    } else {
        const int q = bid - 2048;
        const size_t row = (size_t)q*16 + (tid >> 4);
        const int l16 = tid & 15;
        const size_t base = row*256 + l16*16;
        float v[16];
        {
            short8v a = *(const short8v*)(qpreH + base);
            short8v b = *(const short8v*)(qpreH + base + 8);
            #pragma unroll
            for (int i = 0; i < 8; ++i){ v[i] = h2f((ushort)a[i]); v[8+i] = h2f((ushort)b[i]); }
        }
        float m = v[0];
        #pragma unroll
        for (int i = 1; i < 16; ++i) m = fmaxf(m, v[i]);
        #pragma unroll
        for (int off = 1; off < 16; off <<= 1) m = fmaxf(m, __shfl_xor(m, off));
        float s = 0.f;
        #pragma unroll
        for (int i = 0; i < 16; ++i){ v[i] = fexp(v[i] - m); s += v[i]; }
        #pragma unroll
        for (int off = 1; off < 16; off <<= 1) s += __shfl_xor(s, off);
        float inv = 1.f / s;
        short8v o0, o1;
        #pragma unroll
        for (int i = 0; i < 8; ++i){ o0[i] = (short)f2b(v[i]*inv); o1[i] = (short)f2b(v[8+i]*inv); }
        *(short8v*)(qTb + base) = o0;
        *(short8v*)(qTb + base + 8) = o1;
    }
}

// ---------------- gram4: 4 grams in one launch (g=0..2 chan-att, g=3 KX) ----------------
__global__ __launch_bounds__(256) void gram4_kernel(
        const ushort* __restrict__ P, const ushort* __restrict__ keysb,
        const ushort* __restrict__ S, ushort* __restrict__ part){
    __shared__ ushort As[128*64];
    __shared__ ushort Bs[128*64];
    const int bid = blockIdx.x;
    const int vid = (bid & 7) * (gridDim.x >> 3) + (bid >> 3);
    const int z = vid >> 2;
    const int t = vid & 3;
    const int m0 = (t & 1) * 128, n0 = (t >> 1) * 128;
    const int g = z >> 6;
    const int bb = (z >> 3) & 7;
    const int kc = z & 7;
    const int kbeg = kc * 512;
    const ushort* Abase = (g < 3) ? P + (size_t)g*BCHW : keysb;
    const ushort* Bbase = S + (size_t)((g == 3) ? 0 : g)*BCHW;
    const int tid = threadIdx.x;
    const int l = tid & 63, w = tid >> 6;
    const int wm = (w >> 1) * 64, wn = (w & 1) * 64;
    const int lr8 = l >> 3;
    const int lk = ((l & 7) ^ lr8) << 3;
    const ushort* Ag = Abase + (size_t)bb*CHW + (size_t)(m0 + w*32 + lr8)*4096 + kbeg + lk;
    const ushort* Bg = Bbase + (size_t)bb*CHW + (size_t)(n0 + w*32 + lr8)*4096 + kbeg + lk;
    int rabase[4], raswz[4], rbbase[4], rbswz[4];
    #pragma unroll
    for (int f = 0; f < 4; ++f){
        int ra = wm + f*16 + (l & 15);
        int rb = wn + f*16 + (l & 15);
        rabase[f] = ra*64 + (l>>4)*8;  raswz[f] = (ra & 7) << 3;
        rbbase[f] = rb*64 + (l>>4)*8;  rbswz[f] = (rb & 7) << 3;
    }
    f32x4 acc[4][4] = {};
    for (int kt = 0; kt < 8; ++kt){
        #pragma unroll
        for (int i = 0; i < 4; ++i){
            gload16(Ag + (size_t)i*8*4096 + kt*64, &As[(w*32 + i*8)*64]);
            gload16(Bg + (size_t)i*8*4096 + kt*64, &Bs[(w*32 + i*8)*64]);
        }
        __syncthreads();
        #pragma unroll
        for (int ks = 0; ks < 2; ++ks){
            short8v af[4], bf[4];
            #pragma unroll
            for (int f = 0; f < 4; ++f){
                af[f] = *(const short8v*)&As[(rabase[f] + ks*32) ^ raswz[f]];
                bf[f] = *(const short8v*)&Bs[(rbbase[f] + ks*32) ^ rbswz[f]];
            }
            #pragma unroll
            for (int fi = 0; fi < 4; ++fi)
                #pragma unroll
                for (int fj = 0; fj < 4; ++fj)
                    acc[fi][fj] = __builtin_amdgcn_mfma_f32_16x16x32_bf16(af[fi], bf[fj], acc[fi][fj], 0, 0, 0);
        }
        __syncthreads();
    }
    const int erow = (l >> 4) * 4, ecol = l & 15;
    #pragma unroll
    for (int fi = 0; fi < 4; ++fi){
        #pragma unroll
        for (int r = 0; r < 4; ++r){
            const int m = m0 + wm + fi*16 + erow + r;
            #pragma unroll
            for (int fj = 0; fj < 4; ++fj){
                const int n = n0 + wn + fj*16 + ecol;
                part[((size_t)z << 16) + (size_t)m*256 + n] = f2h(acc[fi][fj][r]);
            }
        }
    }
}

// ---------------- merged: rsa3 (bid<2048) + KX reduce (bid>=2048) ----------------
__global__ __launch_bounds__(256) void rsaR_kernel(const ushort* __restrict__ part,
                                                   float* __restrict__ att,
                                                   float* __restrict__ KX){
    const int bid = blockIdx.x;
    const int tid = threadIdx.x;
    if (bid < 2048){
        const int row = bid;
        const int b = row >> 8;
        const int wid = tid >> 6, lane = tid & 63;
        __shared__ float redm[3][4], reds[3][4];
        float r[3];
        #pragma unroll
        for (int g = 0; g < 3; ++g){
            const size_t base = (((size_t)(g*64 + b*8)) << 16) + (size_t)(row & 255)*256 + tid;
            float v = 0.f;
            #pragma unroll
            for (int kc = 0; kc < 8; ++kc) v += h2f(part[base + ((size_t)kc << 16)]);
            float m = v;
            #pragma unroll
            for (int off = 32; off > 0; off >>= 1) m = fmaxf(m, __shfl_xor(m, off));
            if (lane == 0) redm[g][wid] = m;
            __syncthreads();
            m = fmaxf(fmaxf(redm[g][0], redm[g][1]), fmaxf(redm[g][2], redm[g][3]));
            float e = fexp(v - m);
            float s = e;
            #pragma unroll
            for (int off = 32; off > 0; off >>= 1) s += __shfl_xor(s, off);
            if (lane == 0) reds[g][wid] = s;
            __syncthreads();
            s = reds[g][0] + reds[g][1] + reds[g][2] + reds[g][3];
            r[g] = e / s;
        }
        att[(size_t)row*256 + tid] = r[0] + r[1] + r[2];
    } else {
        int i = (bid - 2048)*256 + tid;
        int b = i >> 16; int r = i & 65535;
        float s = 0.f;
        #pragma unroll
        for (int kc = 0; kc < 8; ++kc)
            s += h2f(part[(((size_t)(192 + b*8 + kc)) << 16) + r]);
        KX[i] = s;
    }
}

// ---------------- small NT gemm 256x256x256 per-batch (f32 VALU) ----------------
template<int ABATCH, int BBATCH, int EPI>
__global__ __launch_bounds__(256) void nt256_kernel(const float* __restrict__ A,
        const float* __restrict__ B, const float* __restrict__ bias,
        const float* __restrict__ att, const float* __restrict__ wdw,
        void* __restrict__ Cout){
    const int bb = blockIdx.z;
    const int m0 = blockIdx.y * 64, n0 = blockIdx.x * 64;
    const float* Ab = ABATCH ? A + (size_t)bb*65536 : A;
    const float* Bb = BBATCH ? B + (size_t)bb*65536 : B;
    __shared__ float Au[32*68];
    __shared__ float Bu[32*68];
    const int tid = threadIdx.x;
    const int tx = tid & 15, ty = tid >> 4;
    const int row = tid >> 2, loff = (tid & 3) * 8;
    float acc[4][4] = {};
    for (int k0 = 0; k0 < 256; k0 += 32){
        float4 a0 = *(const float4*)&Ab[(size_t)(m0+row)*256 + k0 + loff];
        float4 a1 = *(const float4*)&Ab[(size_t)(m0+row)*256 + k0 + loff + 4];
        float4 b0 = *(const float4*)&Bb[(size_t)(n0+row)*256 + k0 + loff];
        float4 b1 = *(const float4*)&Bb[(size_t)(n0+row)*256 + k0 + loff + 4];
        Au[(loff+0)*68 + row] = a0.x;
        Au[(loff+1)*68 + row] = a0.y;
        Au[(loff+2)*68 + row] = a0.z;
        Au[(loff+3)*68 + row] = a0.w;
        Au[(loff+4)*68 + row] = a1.x;
        Au[(loff+5)*68 + row] = a1.y;
        Au[(loff+6)*68 + row] = a1.z;
        Au[(loff+7)*68 + row] = a1.w;
        Bu[(loff+0)*68 + row] = b0.x;
        Bu[(loff+1)*68 + row] = b0.y;
        Bu[(loff+2)*68 + row] = b0.z;
        Bu[(loff+3)*68 + row] = b0.w;
        Bu[(loff+4)*68 + row] = b1.x;
        Bu[(loff+5)*68 + row] = b1.y;
        Bu[(loff+6)*68 + row] = b1.z;
        Bu[(loff+7)*68 + row] = b1.w;
        __syncthreads();
        #pragma unroll
        for (int kk = 0; kk < 32; ++kk){
            float4 av = *(const float4*)&Au[kk*68 + ty*4];
            float4 bv = *(const float4*)&Bu[kk*68 + tx*4];
            float aa[4] = {av.x, av.y, av.z, av.w};
            float bb2[4] = {bv.x, bv.y, bv.z, bv.w};
            #pragma unroll
            for (int i = 0; i < 4; ++i)
                #pragma unroll
                for (int j = 0; j < 4; ++j)
                    acc[i][j] += aa[i]*bb2[j];
        }
        __syncthreads();
    }
    #pragma unroll
    for (int i = 0; i < 4; ++i){
        int m = m0 + ty*4 + i;
        ushort4 uv;
        ushort* up = &uv.x;
        #pragma unroll
        for (int j = 0; j < 4; ++j){
            int n = n0 + tx*4 + j;
            float v = wdw[2*m]*acc[i][j] + wdw[2*m+1]*att[(size_t)bb*65536 + (size_t)n*256 + m];
            up[j] = f2b(v);
        }
        *(ushort4*)&((ushort*)Cout)[(size_t)bb*65536 + (size_t)m*256 + n0 + tx*4] = uv;
    }
}

// ---------------- MFMA NT GEMM (generic, for final out) ----------------
template<int EPI, int KC, int POUT>
__global__ __launch_bounds__(256) void mfma_nt(
        const ushort* __restrict__ A, size_t Abstride, int lda,
        const ushort* __restrict__ B, size_t Bbstride, int ldb,
        void* __restrict__ C, size_t Czstride, int ldc,
        int Kchunk, int ntx, int nty,
        const float* __restrict__ bias, const float* __restrict__ wdw){
    __shared__ ushort As[128*64];
    __shared__ ushort Bs[128*64];
    const int bid = blockIdx.x;
    const int vid = (bid & 7) * (gridDim.x >> 3) + (bid >> 3);
    const int nt = ntx * nty;
    const int z = vid / nt;
    const int t = vid - z * nt;
    const int m0 = (t % nty) * 128, n0 = (t / nty) * 128;
    const int bb = z / KC;
    const int kc = z - bb * KC;
    const int kbeg = kc * Kchunk;
    const int tid = threadIdx.x;
    const int l = tid & 63, w = tid >> 6;
    const int wm = (w >> 1) * 64, wn = (w & 1) * 64;
    const int lr8 = l >> 3;
    const int lk = ((l & 7) ^ lr8) << 3;
    const ushort* Ag = A + (size_t)bb*Abstride + (size_t)(m0 + w*32 + lr8)*lda + kbeg + lk;
    const ushort* Bg = B + (size_t)bb*Bbstride + (size_t)(n0 + w*32 + lr8)*ldb + kbeg + lk;
    int rabase[4], raswz[4], rbbase[4], rbswz[4];
    #pragma unroll
    for (int f = 0; f < 4; ++f){
        int ra = wm + f*16 + (l & 15);
        int rb = wn + f*16 + (l & 15);
        rabase[f] = ra*64 + (l>>4)*8;  raswz[f] = (ra & 7) << 3;
        rbbase[f] = rb*64 + (l>>4)*8;  rbswz[f] = (rb & 7) << 3;
    }
    f32x4 acc[4][4] = {};
    const int ktiles = Kchunk >> 6;
    for (int kt = 0; kt < ktiles; ++kt){
        #pragma unroll
        for (int i = 0; i < 4; ++i){
            gload16(Ag + (size_t)i*8*lda + kt*64, &As[(w*32 + i*8)*64]);
            gload16(Bg + (size_t)i*8*ldb + kt*64, &Bs[(w*32 + i*8)*64]);
        }
        __syncthreads();
        #pragma unroll
        for (int ks = 0; ks < 2; ++ks){
            short8v af[4], bf[4];
            #pragma unroll
            for (int f = 0; f < 4; ++f){
                af[f] = *(const short8v*)&As[(rabase[f] + ks*32) ^ raswz[f]];
                bf[f] = *(const short8v*)&Bs[(rbbase[f] + ks*32) ^ rbswz[f]];
            }
            #pragma unroll
            for (int fi = 0; fi < 4; ++fi)
                #pragma unroll
                for (int fj = 0; fj < 4; ++fj)
                    acc[fi][fj] = __builtin_amdgcn_mfma_f32_16x16x32_bf16(af[fi], bf[fj], acc[fi][fj], 0, 0, 0);
        }
        __syncthreads();
    }
    const int erow = (l >> 4) * 4, ecol = l & 15;
    #pragma unroll
    for (int fi = 0; fi < 4; ++fi){
        #pragma unroll
        for (int r = 0; r < 4; ++r){
            const int m = m0 + wm + fi*16 + erow + r;
            float madd = 0.f;
            if (EPI == 1) madd = bias[m];
            else if (EPI == 3) madd = wdw[2*m]*bias[m];
            #pragma unroll
            for (int fj = 0; fj < 4; ++fj){
                const int n = n0 + wn + fj*16 + ecol;
                float v = acc[fi][fj][r];
                if (EPI == 1 || EPI == 3) v += madd;
                size_t idx = (size_t)z*Czstride + (size_t)m*ldc + n;
                if (POUT == 0) ((float*)C)[idx] = v;
                else           ((ushort*)C)[idx] = f2h(v);
            }
        }
    }
}

// ---------------- host ----------------
extern "C" void kernel_launch(void* const* d_in, const int* in_sizes, int n_in,
                              void* d_out, int out_size, void* d_ws, size_t ws_size,
                              hipStream_t stream){
    const float* x   = (const float*)d_in[0];
    const float* Wk  = (const float*)d_in[1];
    const float* bk  = (const float*)d_in[2];
    const float* Wq  = (const float*)d_in[3];
    const float* bq  = (const float*)d_in[4];
    const float* Wv  = (const float*)d_in[5];
    const float* bv  = (const float*)d_in[6];
    const float* Wr  = (const float*)d_in[7];
    const float* br  = (const float*)d_in[8];
    const float* wdw = (const float*)d_in[9];
    float* out = (float*)d_out;

    char* w = (char*)d_ws;
    ushort* S     = (ushort*)w; w += (size_t)3*BCHW*2;         // S0=xb, S1=L1, S2=L2
    ushort* xTb   = (ushort*)w; w += (size_t)BCHW*2;
    ushort* P     = (ushort*)w; w += (size_t)3*BCHW*2;         // P0,P1,P2 (live thru gram4)
    ushort* keysb = (ushort*)w; w += (size_t)BCHW*2;
    ushort* qTb   = (ushort*)w; w += (size_t)BCHW*2;
    char*   preg  = w;          w += (size_t)4*64*65536*2;     // FreH+qpreH alias / gram4 partials
    float*  att   = (float*)w;  w += (size_t)BB_*65536*4;
    float*  KX    = (float*)w;  w += (size_t)BB_*65536*4;
    ushort* Mbb   = (ushort*)w; w += (size_t)BB_*65536*2;
    ushort* Wkb   = (ushort*)w; w += 65536*2;
    ushort* Wqb   = (ushort*)w; w += 65536*2;
    float*  Wrv   = (float*)w;  w += 65536*4;
    float*  brc   = (float*)w;  w += 256*4;
    ushort* partH = (ushort*)preg;            // gram4 partials f16
    ushort* FreH  = (ushort*)preg;            // keys logits f16 (BCHW)
    ushort* qpreH = FreH + (size_t)BCHW;      // q logits f16 (BCHW)

    Taps5 T3{}, T5{};
    {
        double g[5], s;
        s = 0; for (int i = 0; i < 3; ++i){ double d = i - 1.0; g[i] = exp(-d*d/(2.0*1.6*1.6)); s += g[i]; }
        for (int i = 0; i < 3; ++i) T3.t[i] = (float)(g[i]/s);
        double sig = 1.6 * pow(2.0, 1.0/3.0);
        s = 0; for (int i = 0; i < 5; ++i){ double d = i - 2.0; g[i] = exp(-d*d/(2.0*sig*sig)); s += g[i]; }
        for (int i = 0; i < 5; ++i) T5.t[i] = (float)(g[i]/s);
    }

    const dim3 blk(256);

    // K1: prepx | plane6 interleaved by parity (4096) + prepw tail (160)
    prep_all<<<4256, blk, 0, stream>>>(x, Wk, Wq, Wr, Wv, bv, br,
                                       S, xTb, P, S + (size_t)BCHW, S + (size_t)2*BCHW,
                                       Wkb, Wqb, brc, Wrv, T3, T5);

    // K2: keys GEMM (512) + qpre GEMM (512) — uniform-resource body
    kq2_kernel<<<1024, blk, 0, stream>>>(Wkb, xTb, Wqb, bk, bq, FreH, qpreH);

    // K3: keys rowsm (2048) + q softmax-256 (2048)
    sm2_kernel<<<4096, blk, 0, stream>>>(FreH, qpreH, keysb, qTb);

    // K4: 4 grams in one launch (chan-att x3 + KX), 1024 blocks XCD-swizzled
    gram4_kernel<<<1024, blk, 0, stream>>>(P, keysb, S, partH);

    // K5: att softmax-accumulate (bid<2048) + KX reduce (bid>=2048)
    rsaR_kernel<<<4096, blk, 0, stream>>>(partH, att, KX);

    // K6: Mbb[b,m,k] = bf16( wdw0[m]*(Wrv@KX^T) + wdw1[m]*att[b,k,m] )
    nt256_kernel<0,1,1><<<dim3(4,4,8), blk, 0, stream>>>(Wrv, KX, nullptr, att, wdw, Mbb);

    // K7: out = Mbb @ qT^T + wdw0*(br + Wr@bv)
    mfma_nt<3,1,0><<<512, blk, 0, stream>>>(Mbb, 65536, 256, qTb, CHW, 256,
                                            out, CHW, 4096, 256, 32, 2, brc, wdw);
}

// Round 16
// 143.804 us; speedup vs baseline: 1.0229x; 1.0229x over previous
//
#include <hip/hip_runtime.h>
#include <math.h>

#define BB_ 8
#define CC_ 256
#define HWSZ 4096            // 64*64
#define CHW (CC_*HWSZ)       // 1,048,576
#define BCHW (BB_*CHW)       // 8,388,608

typedef __attribute__((ext_vector_type(8))) short short8v;
typedef __attribute__((ext_vector_type(4))) float f32x4;

struct Taps5 { float t[5]; };

__device__ inline ushort f2b(float f){
    uint u = __float_as_uint(f);
    u += 0x7FFF + ((u >> 16) & 1);
    return (ushort)(u >> 16);
}
__device__ inline float b2f(ushort u){
    return __uint_as_float(((uint)u) << 16);
}
__device__ inline ushort f2h(float f){
    _Float16 h = (_Float16)f; ushort u; __builtin_memcpy(&u, &h, 2); return u;
}
__device__ inline float h2f(ushort u){
    _Float16 h; __builtin_memcpy(&h, &u, 2); return (float)h;
}
// fast exp: exp(x) = 2^(x*log2e) via native v_exp_f32
__device__ __forceinline__ float fexp(float x){
    return __builtin_amdgcn_exp2f(x * 1.44269504088896340736f);
}
// async 16B global -> LDS (linear dest = wave-uniform base + lane*16)
__device__ __forceinline__ void gload16(const ushort* g, ushort* l){
    __builtin_amdgcn_global_load_lds(
        (const __attribute__((address_space(1))) void*)g,
        (__attribute__((address_space(3))) void*)l, 16, 0, 0);
}

// ================= K1: mega prep (prepx 2048 | plane6 2048 | prepw 160) =================
__global__ __launch_bounds__(256) void prep_all(const float* __restrict__ x,
        const float* __restrict__ Wk, const float* __restrict__ Wq,
        const float* __restrict__ Wr, const float* __restrict__ Wv,
        const float* __restrict__ bv, const float* __restrict__ br,
        ushort* __restrict__ xb, ushort* __restrict__ xTb,
        ushort* __restrict__ P, ushort* __restrict__ S1, ushort* __restrict__ S2,
        ushort* __restrict__ Wkb, ushort* __restrict__ Wqb,
        float* __restrict__ brc, float* __restrict__ Wrv,
        Taps5 t3, Taps5 t5){
    __shared__ float smem[64*65];
    const int bid = blockIdx.x;
    const int tid = threadIdx.x;

    if (bid < 2048){
        // ---- prepx role ----
        const int b = bid >> 8, c0 = ((bid >> 6) & 3)*64, h0 = (bid & 63)*64;
        const float* xp = x + (size_t)b*CHW;
        float (*T)[65] = (float(*)[65])smem;
        const int cl = tid >> 4;
        const int hl = (tid & 15) * 4;
        #pragma unroll
        for (int p = 0; p < 4; ++p){
            int c = c0 + p*16 + cl;
            float4 v = *(const float4*)&xp[(size_t)c*4096 + h0 + hl];
            ushort4 u; u.x = f2b(v.x); u.y = f2b(v.y); u.z = f2b(v.z); u.w = f2b(v.w);
            *(ushort4*)&xb[(size_t)b*CHW + (size_t)c*4096 + h0 + hl] = u;
            T[p*16+cl][hl+0] = v.x;
            T[p*16+cl][hl+1] = v.y;
            T[p*16+cl][hl+2] = v.z;
            T[p*16+cl][hl+3] = v.w;
        }
        __syncthreads();
        const int hr = tid >> 2;
        const int cs = (tid & 3) * 16;
        short8v o0, o1;
        #pragma unroll
        for (int i = 0; i < 8; ++i) o0[i] = (short)f2b(T[cs+i][hr]);
        #pragma unroll
        for (int i = 0; i < 8; ++i) o1[i] = (short)f2b(T[cs+8+i][hr]);
        ushort* dst = xTb + (size_t)b*CHW + (size_t)(h0+hr)*256 + c0 + cs;
        *(short8v*)dst = o0;
        *(short8v*)(dst+8) = o1;
        return;
    }
    if (bid < 4096){
        // ---- plane6 role ----
        const size_t base = (size_t)(bid - 2048) * HWSZ;
        const int c = tid & 63, rb = tid >> 6;
        float* bndA = smem;
        float* bndB = smem + 512;
        float* red  = smem + 1536;
        float v[16];
        #pragma unroll
        for (int i = 0; i < 16; ++i) v[i] = x[base + (rb*16 + i)*64 + c];
        float h3[16];
        #pragma unroll
        for (int i = 0; i < 16; ++i){
            float l = __shfl(v[i], c-1, 64); l = (c > 0)  ? l : 0.f;
            float r = __shfl(v[i], c+1, 64); r = (c < 63) ? r : 0.f;
            h3[i] = t3.t[0]*l + t3.t[1]*v[i] + t3.t[2]*r;
        }
        bndA[(rb*2+0)*64 + c] = h3[0]; bndA[(rb*2+1)*64 + c] = h3[15];
        __syncthreads();
        const float upA = (rb > 0) ? bndA[((rb-1)*2+1)*64 + c] : 0.f;
        const float dnA = (rb < 3) ? bndA[((rb+1)*2+0)*64 + c] : 0.f;
        float g1[16];
        #pragma unroll
        for (int i = 0; i < 16; ++i){
            float a = (i > 0)  ? h3[i-1] : upA;
            float b = (i < 15) ? h3[i+1] : dnA;
            g1[i] = t3.t[0]*a + t3.t[1]*h3[i] + t3.t[2]*b;
        }
        #pragma unroll
        for (int i = 0; i < 16; ++i){
            float m2 = __shfl(g1[i], c-2, 64); m2 = (c > 1)  ? m2 : 0.f;
            float m1 = __shfl(g1[i], c-1, 64); m1 = (c > 0)  ? m1 : 0.f;
            float p1 = __shfl(g1[i], c+1, 64); p1 = (c < 63) ? p1 : 0.f;
            float p2 = __shfl(g1[i], c+2, 64); p2 = (c < 62) ? p2 : 0.f;
            h3[i] = t5.t[0]*m2 + t5.t[1]*m1 + t5.t[2]*g1[i] + t5.t[3]*p1 + t5.t[4]*p2;
        }
        bndB[(rb*4+0)*64 + c] = h3[0];  bndB[(rb*4+1)*64 + c] = h3[1];
        bndB[(rb*4+2)*64 + c] = h3[14]; bndB[(rb*4+3)*64 + c] = h3[15];
        __syncthreads();
        const float u2 = (rb > 0) ? bndB[((rb-1)*4+2)*64 + c] : 0.f;
        const float u1 = (rb > 0) ? bndB[((rb-1)*4+3)*64 + c] : 0.f;
        const float d1 = (rb < 3) ? bndB[((rb+1)*4+0)*64 + c] : 0.f;
        const float d2 = (rb < 3) ? bndB[((rb+1)*4+1)*64 + c] : 0.f;
        float g2[16];
        #pragma unroll
        for (int i = 0; i < 16; ++i){
            float a = (i >= 2) ? h3[i-2] : (i == 1 ? u1 : u2);
            float b = (i >= 1) ? h3[i-1] : u1;
            float d = (i < 15) ? h3[i+1] : d1;
            float e = (i < 14) ? h3[i+2] : (i == 14 ? d1 : d2);
            g2[i] = t5.t[0]*a + t5.t[1]*b + t5.t[2]*h3[i] + t5.t[3]*d + t5.t[4]*e;
        }
        const size_t orow = base + (size_t)rb*16*64 + c;
        #pragma unroll
        for (int i = 0; i < 16; ++i){
            S1[orow + i*64] = f2b(v[i] - g1[i]);
            S2[orow + i*64] = f2b(g1[i] - g2[i]);
        }
        const int wid = tid >> 6, lane = tid & 63;
        #pragma unroll
        for (int g = 0; g < 3; ++g){
            float val[16];
            #pragma unroll
            for (int i = 0; i < 16; ++i)
                val[i] = (g == 0) ? v[i] : (g == 1 ? v[i] - g1[i] : g1[i] - g2[i]);
            float mx = val[0];
            #pragma unroll
            for (int i = 1; i < 16; ++i) mx = fmaxf(mx, val[i]);
            #pragma unroll
            for (int off = 32; off > 0; off >>= 1) mx = fmaxf(mx, __shfl_xor(mx, off));
            if (lane == 0) red[g*8 + wid] = mx;
            __syncthreads();
            mx = fmaxf(fmaxf(red[g*8+0], red[g*8+1]), fmaxf(red[g*8+2], red[g*8+3]));
            float s = 0.f;
            #pragma unroll
            for (int i = 0; i < 16; ++i){ val[i] = fexp(val[i] - mx); s += val[i]; }
            #pragma unroll
            for (int off = 32; off > 0; off >>= 1) s += __shfl_xor(s, off);
            if (lane == 0) red[g*8 + 4 + wid] = s;
            __syncthreads();
            s = red[g*8+4] + red[g*8+5] + red[g*8+6] + red[g*8+7];
            float inv = 1.f / s;
            ushort* Pg = P + (size_t)g*BCHW;
            #pragma unroll
            for (int i = 0; i < 16; ++i) Pg[orow + i*64] = f2b(val[i]*inv);
        }
        return;
    }
    // ---- prepw role ----
    const int blk = bid - 4096;
    if (blk < 128){
        const float* src = (blk < 64) ? Wk : Wq;
        ushort* dst = (blk < 64) ? Wkb : Wqb;
        int i = (blk & 63)*256 + tid;
        float4 v = *(const float4*)&src[i*4];
        ushort4 u; u.x = f2b(v.x); u.y = f2b(v.y); u.z = f2b(v.z); u.w = f2b(v.w);
        *(ushort4*)&dst[i*4] = u;
        return;
    }
    if (blk < 144){
        int m = (blk - 128)*16 + (tid >> 4);
        int l16 = tid & 15;
        float s = 0.f;
        #pragma unroll
        for (int t = 0; t < 4; ++t){
            float4 a = *(const float4*)&Wr[(size_t)m*256 + l16*16 + t*4];
            float4 b = *(const float4*)&bv[l16*16 + t*4];
            s += a.x*b.x + a.y*b.y + a.z*b.z + a.w*b.w;
        }
        #pragma unroll
        for (int off = 1; off < 16; off <<= 1) s += __shfl_xor(s, off);
        if (l16 == 0) brc[m] = br[m] + s;
        return;
    }
    {
        const int t = blk - 144;
        const int m0 = (t >> 2) * 64, n0 = (t & 3) * 64;
        float* As = smem;
        float* Bs = smem + 2112;
        const int tx = tid & 15, ty = tid >> 4;
        float acc[4][4] = {};
        for (int k0 = 0; k0 < 256; k0 += 32){
            int kk = tid & 31, ml = tid >> 5;
            #pragma unroll
            for (int r = 0; r < 8; ++r){
                int m = ml + r*8;
                As[kk*66 + m] = Wr[(size_t)(m0+m)*256 + k0 + kk];
            }
            int j = tid & 63, kg = tid >> 6;
            #pragma unroll
            for (int r = 0; r < 8; ++r){
                int kk2 = kg + r*4;
                Bs[kk2*64 + j] = Wv[(size_t)(k0+kk2)*256 + n0 + j];
            }
            __syncthreads();
            #pragma unroll
            for (int kk2 = 0; kk2 < 32; ++kk2){
                float4 bv4 = *(const float4*)&Bs[kk2*64 + tx*4];
                float av[4] = {As[kk2*66+ty*4+0], As[kk2*66+ty*4+1], As[kk2*66+ty*4+2], As[kk2*66+ty*4+3]};
                float bw[4] = {bv4.x, bv4.y, bv4.z, bv4.w};
                #pragma unroll
                for (int i = 0; i < 4; ++i)
                    #pragma unroll
                    for (int j2 = 0; j2 < 4; ++j2)
                        acc[i][j2] += av[i]*bw[j2];
            }
            __syncthreads();
        }
        #pragma unroll
        for (int i = 0; i < 4; ++i){
            float4 wv4 = {acc[i][0], acc[i][1], acc[i][2], acc[i][3]};
            *(float4*)&Wrv[(size_t)(m0+ty*4+i)*256 + n0 + tx*4] = wv4;
        }
    }
}

// ================= K2: kq2 — keys GEMM (512) + qpre GEMM (512), uniform body =================
__global__ __launch_bounds__(256) void kq2_kernel(const ushort* __restrict__ Wkb,
        const ushort* __restrict__ xTb, const ushort* __restrict__ Wqb,
        const float* __restrict__ bk, const float* __restrict__ bq,
        ushort* __restrict__ FreH, ushort* __restrict__ qpreH){
    __shared__ ushort As[128*64];
    __shared__ ushort Bs[128*64];
    const int bid = blockIdx.x;
    const int vid = (bid & 7)*128 + (bid >> 3);   // 1024 blocks, bijective
    const int tid = threadIdx.x;
    const int l = tid & 63, w = tid >> 6;
    const int wm = (w >> 1) * 64, wn = (w & 1) * 64;
    const int lr8 = l >> 3;
    const int lk = ((l & 7) ^ lr8) << 3;
    const bool keys = (vid < 512);
    const int sub = keys ? vid : vid - 512;
    const int b = sub >> 6;
    const int t = sub & 63;
    const int m0 = keys ? (t & 1)*128 : (t >> 1)*128;
    const int n0 = keys ? (t >> 1)*128 : (t & 1)*128;
    const ushort* Ag = keys
        ? Wkb + (size_t)(m0 + w*32 + lr8)*256 + lk
        : xTb + (size_t)b*CHW + (size_t)(m0 + w*32 + lr8)*256 + lk;
    const ushort* Bg = keys
        ? xTb + (size_t)b*CHW + (size_t)(n0 + w*32 + lr8)*256 + lk
        : Wqb + (size_t)(n0 + w*32 + lr8)*256 + lk;
    int rabase[4], raswz[4], rbbase[4], rbswz[4];
    #pragma unroll
    for (int f = 0; f < 4; ++f){
        int ra = wm + f*16 + (l & 15);
        int rb = wn + f*16 + (l & 15);
        rabase[f] = ra*64 + (l>>4)*8;  raswz[f] = (ra & 7) << 3;
        rbbase[f] = rb*64 + (l>>4)*8;  rbswz[f] = (rb & 7) << 3;
    }
    f32x4 acc[4][4] = {};
    for (int kt = 0; kt < 4; ++kt){
        #pragma unroll
        for (int i = 0; i < 4; ++i){
            gload16(Ag + (size_t)i*8*256 + kt*64, &As[(w*32 + i*8)*64]);
            gload16(Bg + (size_t)i*8*256 + kt*64, &Bs[(w*32 + i*8)*64]);
        }
        __syncthreads();
        #pragma unroll
        for (int ks = 0; ks < 2; ++ks){
            short8v af[4], bf[4];
            #pragma unroll
            for (int f = 0; f < 4; ++f){
                af[f] = *(const short8v*)&As[(rabase[f] + ks*32) ^ raswz[f]];
                bf[f] = *(const short8v*)&Bs[(rbbase[f] + ks*32) ^ rbswz[f]];
            }
            #pragma unroll
            for (int fi = 0; fi < 4; ++fi)
                #pragma unroll
                for (int fj = 0; fj < 4; ++fj)
                    acc[fi][fj] = __builtin_amdgcn_mfma_f32_16x16x32_bf16(af[fi], bf[fj], acc[fi][fj], 0, 0, 0);
        }
        __syncthreads();
    }
    const int erow = (l >> 4) * 4, ecol = l & 15;
    if (keys){
        #pragma unroll
        for (int fi = 0; fi < 4; ++fi){
            #pragma unroll
            for (int r = 0; r < 4; ++r){
                const int m = m0 + wm + fi*16 + erow + r;
                const float madd = bk[m];
                #pragma unroll
                for (int fj = 0; fj < 4; ++fj){
                    const int n = n0 + wn + fj*16 + ecol;
                    FreH[(size_t)b*CHW + (size_t)m*4096 + n] = f2h(acc[fi][fj][r] + madd);
                }
            }
        }
    } else {
        #pragma unroll
        for (int fi = 0; fi < 4; ++fi){
            #pragma unroll
            for (int r = 0; r < 4; ++r){
                const int m = m0 + wm + fi*16 + erow + r;
                #pragma unroll
                for (int fj = 0; fj < 4; ++fj){
                    const int n = n0 + wn + fj*16 + ecol;
                    qpreH[(size_t)b*CHW + (size_t)m*256 + n] = f2h(acc[fi][fj][r] + bq[n]);
                }
            }
        }
    }
}

// ================= K3: sm2 — keys rowsm over 4096 (bid<2048) + q softmax over 256 =================
__global__ __launch_bounds__(256) void sm2_kernel(const ushort* __restrict__ FreH,
        const ushort* __restrict__ qpreH,
        ushort* __restrict__ keysb, ushort* __restrict__ qTb){
    const int bid = blockIdx.x;
    const int tid = threadIdx.x;
    if (bid < 2048){
        const size_t base = (size_t)bid * HWSZ + tid * 16;
        float v[16];
        {
            short8v a = *(const short8v*)(FreH + base);
            short8v b = *(const short8v*)(FreH + base + 8);
            #pragma unroll
            for (int i = 0; i < 8; ++i){ v[i] = h2f((ushort)a[i]); v[8+i] = h2f((ushort)b[i]); }
        }
        float m = v[0];
        #pragma unroll
        for (int i = 1; i < 16; ++i) m = fmaxf(m, v[i]);
        #pragma unroll
        for (int off = 32; off > 0; off >>= 1) m = fmaxf(m, __shfl_xor(m, off));
        __shared__ float redm[4], reds[4];
        int wid = tid >> 6, lane = tid & 63;
        if (lane == 0) redm[wid] = m;
        __syncthreads();
        m = fmaxf(fmaxf(redm[0], redm[1]), fmaxf(redm[2], redm[3]));
        float s = 0.f;
        #pragma unroll
        for (int i = 0; i < 16; ++i){ v[i] = fexp(v[i] - m); s += v[i]; }
        #pragma unroll
        for (int off = 32; off > 0; off >>= 1) s += __shfl_xor(s, off);
        if (lane == 0) reds[wid] = s;
        __syncthreads();
        s = reds[0] + reds[1] + reds[2] + reds[3];
        float inv = 1.f / s;
        short8v o0, o1;
        #pragma unroll
        for (int i = 0; i < 8; ++i){ o0[i] = (short)f2b(v[i]*inv); o1[i] = (short)f2b(v[8+i]*inv); }
        ushort* op = keysb + base;
        *(short8v*)op = o0; *(short8v*)(op+8) = o1;
    } else {
        const int q = bid - 2048;
        const size_t row = (size_t)q*16 + (tid >> 4);
        const int l16 = tid & 15;
        const size_t base = row*256 + l16*16;
        float v[16];
        {
            short8v a = *(const short8v*)(qpreH + base);
            short8v b = *(const short8v*)(qpreH + base + 8);
            #pragma unroll
            for (int i = 0; i < 8; ++i){ v[i] = h2f((ushort)a[i]); v[8+i] = h2f((ushort)b[i]); }
        }
        float m = v[0];
        #pragma unroll
        for (int i = 1; i < 16; ++i) m = fmaxf(m, v[i]);
        #pragma unroll
        for (int off = 1; off < 16; off <<= 1) m = fmaxf(m, __shfl_xor(m, off));
        float s = 0.f;
        #pragma unroll
        for (int i = 0; i < 16; ++i){ v[i] = fexp(v[i] - m); s += v[i]; }
        #pragma unroll
        for (int off = 1; off < 16; off <<= 1) s += __shfl_xor(s, off);
        float inv = 1.f / s;
        short8v o0, o1;
        #pragma unroll
        for (int i = 0; i < 8; ++i){ o0[i] = (short)f2b(v[i]*inv); o1[i] = (short)f2b(v[8+i]*inv); }
        *(short8v*)(qTb + base) = o0;
        *(short8v*)(qTb + base + 8) = o1;
    }
}

// ---------------- gram4: 4 grams in one launch (g=0..2 chan-att, g=3 KX) ----------------
__global__ __launch_bounds__(256) void gram4_kernel(
        const ushort* __restrict__ P, const ushort* __restrict__ keysb,
        const ushort* __restrict__ S, ushort* __restrict__ part){
    __shared__ ushort As[128*64];
    __shared__ ushort Bs[128*64];
    const int bid = blockIdx.x;
    const int vid = (bid & 7) * (gridDim.x >> 3) + (bid >> 3);
    const int z = vid >> 2;
    const int t = vid & 3;
    const int m0 = (t & 1) * 128, n0 = (t >> 1) * 128;
    const int g = z >> 6;
    const int bb = (z >> 3) & 7;
    const int kc = z & 7;
    const int kbeg = kc * 512;
    const ushort* Abase = (g < 3) ? P + (size_t)g*BCHW : keysb;
    const ushort* Bbase = S + (size_t)((g == 3) ? 0 : g)*BCHW;
    const int tid = threadIdx.x;
    const int l = tid & 63, w = tid >> 6;
    const int wm = (w >> 1) * 64, wn = (w & 1) * 64;
    const int lr8 = l >> 3;
    const int lk = ((l & 7) ^ lr8) << 3;
    const ushort* Ag = Abase + (size_t)bb*CHW + (size_t)(m0 + w*32 + lr8)*4096 + kbeg + lk;
    const ushort* Bg = Bbase + (size_t)bb*CHW + (size_t)(n0 + w*32 + lr8)*4096 + kbeg + lk;
    int rabase[4], raswz[4], rbbase[4], rbswz[4];
    #pragma unroll
    for (int f = 0; f < 4; ++f){
        int ra = wm + f*16 + (l & 15);
        int rb = wn + f*16 + (l & 15);
        rabase[f] = ra*64 + (l>>4)*8;  raswz[f] = (ra & 7) << 3;
        rbbase[f] = rb*64 + (l>>4)*8;  rbswz[f] = (rb & 7) << 3;
    }
    f32x4 acc[4][4] = {};
    for (int kt = 0; kt < 8; ++kt){
        #pragma unroll
        for (int i = 0; i < 4; ++i){
            gload16(Ag + (size_t)i*8*4096 + kt*64, &As[(w*32 + i*8)*64]);
            gload16(Bg + (size_t)i*8*4096 + kt*64, &Bs[(w*32 + i*8)*64]);
        }
        __syncthreads();
        #pragma unroll
        for (int ks = 0; ks < 2; ++ks){
            short8v af[4], bf[4];
            #pragma unroll
            for (int f = 0; f < 4; ++f){
                af[f] = *(const short8v*)&As[(rabase[f] + ks*32) ^ raswz[f]];
                bf[f] = *(const short8v*)&Bs[(rbbase[f] + ks*32) ^ rbswz[f]];
            }
            #pragma unroll
            for (int fi = 0; fi < 4; ++fi)
                #pragma unroll
                for (int fj = 0; fj < 4; ++fj)
                    acc[fi][fj] = __builtin_amdgcn_mfma_f32_16x16x32_bf16(af[fi], bf[fj], acc[fi][fj], 0, 0, 0);
        }
        __syncthreads();
    }
    const int erow = (l >> 4) * 4, ecol = l & 15;
    #pragma unroll
    for (int fi = 0; fi < 4; ++fi){
        #pragma unroll
        for (int r = 0; r < 4; ++r){
            const int m = m0 + wm + fi*16 + erow + r;
            #pragma unroll
            for (int fj = 0; fj < 4; ++fj){
                const int n = n0 + wn + fj*16 + ecol;
                part[((size_t)z << 16) + (size_t)m*256 + n] = f2h(acc[fi][fj][r]);
            }
        }
    }
}

// ---------------- merged: rsa3 (bid<2048) + KX reduce (bid>=2048) ----------------
__global__ __launch_bounds__(256) void rsaR_kernel(const ushort* __restrict__ part,
                                                   float* __restrict__ att,
                                                   float* __restrict__ KX){
    const int bid = blockIdx.x;
    const int tid = threadIdx.x;
    if (bid < 2048){
        const int row = bid;
        const int b = row >> 8;
        const int wid = tid >> 6, lane = tid & 63;
        __shared__ float redm[3][4], reds[3][4];
        float r[3];
        #pragma unroll
        for (int g = 0; g < 3; ++g){
            const size_t base = (((size_t)(g*64 + b*8)) << 16) + (size_t)(row & 255)*256 + tid;
            float v = 0.f;
            #pragma unroll
            for (int kc = 0; kc < 8; ++kc) v += h2f(part[base + ((size_t)kc << 16)]);
            float m = v;
            #pragma unroll
            for (int off = 32; off > 0; off >>= 1) m = fmaxf(m, __shfl_xor(m, off));
            if (lane == 0) redm[g][wid] = m;
            __syncthreads();
            m = fmaxf(fmaxf(redm[g][0], redm[g][1]), fmaxf(redm[g][2], redm[g][3]));
            float e = fexp(v - m);
            float s = e;
            #pragma unroll
            for (int off = 32; off > 0; off >>= 1) s += __shfl_xor(s, off);
            if (lane == 0) reds[g][wid] = s;
            __syncthreads();
            s = reds[g][0] + reds[g][1] + reds[g][2] + reds[g][3];
            r[g] = e / s;
        }
        att[(size_t)row*256 + tid] = r[0] + r[1] + r[2];
    } else {
        int i = (bid - 2048)*256 + tid;
        int b = i >> 16; int r = i & 65535;
        float s = 0.f;
        #pragma unroll
        for (int kc = 0; kc < 8; ++kc)
            s += h2f(part[(((size_t)(192 + b*8 + kc)) << 16) + r]);
        KX[i] = s;
    }
}

// ---------------- small NT gemm 256x256x256 per-batch (f32 VALU) ----------------
template<int ABATCH, int BBATCH, int EPI>
__global__ __launch_bounds__(256) void nt256_kernel(const float* __restrict__ A,
        const float* __restrict__ B, const float* __restrict__ bias,
        const float* __restrict__ att, const float* __restrict__ wdw,
        void* __restrict__ Cout){
    const int bb = blockIdx.z;
    const int m0 = blockIdx.y * 64, n0 = blockIdx.x * 64;
    const float* Ab = ABATCH ? A + (size_t)bb*65536 : A;
    const float* Bb = BBATCH ? B + (size_t)bb*65536 : B;
    __shared__ float Au[32*68];
    __shared__ float Bu[32*68];
    const int tid = threadIdx.x;
    const int tx = tid & 15, ty = tid >> 4;
    const int row = tid >> 2, loff = (tid & 3) * 8;
    float acc[4][4] = {};
    for (int k0 = 0; k0 < 256; k0 += 32){
        float4 a0 = *(const float4*)&Ab[(size_t)(m0+row)*256 + k0 + loff];
        float4 a1 = *(const float4*)&Ab[(size_t)(m0+row)*256 + k0 + loff + 4];
        float4 b0 = *(const float4*)&Bb[(size_t)(n0+row)*256 + k0 + loff];
        float4 b1 = *(const float4*)&Bb[(size_t)(n0+row)*256 + k0 + loff + 4];
        Au[(loff+0)*68 + row] = a0.x;
        Au[(loff+1)*68 + row] = a0.y;
        Au[(loff+2)*68 + row] = a0.z;
        Au[(loff+3)*68 + row] = a0.w;
        Au[(loff+4)*68 + row] = a1.x;
        Au[(loff+5)*68 + row] = a1.y;
        Au[(loff+6)*68 + row] = a1.z;
        Au[(loff+7)*68 + row] = a1.w;
        Bu[(loff+0)*68 + row] = b0.x;
        Bu[(loff+1)*68 + row] = b0.y;
        Bu[(loff+2)*68 + row] = b0.z;
        Bu[(loff+3)*68 + row] = b0.w;
        Bu[(loff+4)*68 + row] = b1.x;
        Bu[(loff+5)*68 + row] = b1.y;
        Bu[(loff+6)*68 + row] = b1.z;
        Bu[(loff+7)*68 + row] = b1.w;
        __syncthreads();
        #pragma unroll
        for (int kk = 0; kk < 32; ++kk){
            float4 av = *(const float4*)&Au[kk*68 + ty*4];
            float4 bv = *(const float4*)&Bu[kk*68 + tx*4];
            float aa[4] = {av.x, av.y, av.z, av.w};
            float bb2[4] = {bv.x, bv.y, bv.z, bv.w};
            #pragma unroll
            for (int i = 0; i < 4; ++i)
                #pragma unroll
                for (int j = 0; j < 4; ++j)
                    acc[i][j] += aa[i]*bb2[j];
        }
        __syncthreads();
    }
    #pragma unroll
    for (int i = 0; i < 4; ++i){
        int m = m0 + ty*4 + i;
        ushort4 uv;
        ushort* up = &uv.x;
        #pragma unroll
        for (int j = 0; j < 4; ++j){
            int n = n0 + tx*4 + j;
            float v = wdw[2*m]*acc[i][j] + wdw[2*m+1]*att[(size_t)bb*65536 + (size_t)n*256 + m];
            up[j] = f2b(v);
        }
        *(ushort4*)&((ushort*)Cout)[(size_t)bb*65536 + (size_t)m*256 + n0 + tx*4] = uv;
    }
}

// ---------------- MFMA NT GEMM (generic, for final out) ----------------
template<int EPI, int KC, int POUT>
__global__ __launch_bounds__(256) void mfma_nt(
        const ushort* __restrict__ A, size_t Abstride, int lda,
        const ushort* __restrict__ B, size_t Bbstride, int ldb,
        void* __restrict__ C, size_t Czstride, int ldc,
        int Kchunk, int ntx, int nty,
        const float* __restrict__ bias, const float* __restrict__ wdw){
    __shared__ ushort As[128*64];
    __shared__ ushort Bs[128*64];
    const int bid = blockIdx.x;
    const int vid = (bid & 7) * (gridDim.x >> 3) + (bid >> 3);
    const int nt = ntx * nty;
    const int z = vid / nt;
    const int t = vid - z * nt;
    const int m0 = (t % nty) * 128, n0 = (t / nty) * 128;
    const int bb = z / KC;
    const int kc = z - bb * KC;
    const int kbeg = kc * Kchunk;
    const int tid = threadIdx.x;
    const int l = tid & 63, w = tid >> 6;
    const int wm = (w >> 1) * 64, wn = (w & 1) * 64;
    const int lr8 = l >> 3;
    const int lk = ((l & 7) ^ lr8) << 3;
    const ushort* Ag = A + (size_t)bb*Abstride + (size_t)(m0 + w*32 + lr8)*lda + kbeg + lk;
    const ushort* Bg = B + (size_t)bb*Bbstride + (size_t)(n0 + w*32 + lr8)*ldb + kbeg + lk;
    int rabase[4], raswz[4], rbbase[4], rbswz[4];
    #pragma unroll
    for (int f = 0; f < 4; ++f){
        int ra = wm + f*16 + (l & 15);
        int rb = wn + f*16 + (l & 15);
        rabase[f] = ra*64 + (l>>4)*8;  raswz[f] = (ra & 7) << 3;
        rbbase[f] = rb*64 + (l>>4)*8;  rbswz[f] = (rb & 7) << 3;
    }
    f32x4 acc[4][4] = {};
    const int ktiles = Kchunk >> 6;
    for (int kt = 0; kt < ktiles; ++kt){
        #pragma unroll
        for (int i = 0; i < 4; ++i){
            gload16(Ag + (size_t)i*8*lda + kt*64, &As[(w*32 + i*8)*64]);
            gload16(Bg + (size_t)i*8*ldb + kt*64, &Bs[(w*32 + i*8)*64]);
        }
        __syncthreads();
        #pragma unroll
        for (int ks = 0; ks < 2; ++ks){
            short8v af[4], bf[4];
            #pragma unroll
            for (int f = 0; f < 4; ++f){
                af[f] = *(const short8v*)&As[(rabase[f] + ks*32) ^ raswz[f]];
                bf[f] = *(const short8v*)&Bs[(rbbase[f] + ks*32) ^ rbswz[f]];
            }
            #pragma unroll
            for (int fi = 0; fi < 4; ++fi)
                #pragma unroll
                for (int fj = 0; fj < 4; ++fj)
                    acc[fi][fj] = __builtin_amdgcn_mfma_f32_16x16x32_bf16(af[fi], bf[fj], acc[fi][fj], 0, 0, 0);
        }
        __syncthreads();
    }
    const int erow = (l >> 4) * 4, ecol = l & 15;
    #pragma unroll
    for (int fi = 0; fi < 4; ++fi){
        #pragma unroll
        for (int r = 0; r < 4; ++r){
            const int m = m0 + wm + fi*16 + erow + r;
            float madd = 0.f;
            if (EPI == 1) madd = bias[m];
            else if (EPI == 3) madd = wdw[2*m]*bias[m];
            #pragma unroll
            for (int fj = 0; fj < 4; ++fj){
                const int n = n0 + wn + fj*16 + ecol;
                float v = acc[fi][fj][r];
                if (EPI == 1 || EPI == 3) v += madd;
                size_t idx = (size_t)z*Czstride + (size_t)m*ldc + n;
                if (POUT == 0) ((float*)C)[idx] = v;
                else           ((ushort*)C)[idx] = f2h(v);
            }
        }
    }
}

// ---------------- host ----------------
extern "C" void kernel_launch(void* const* d_in, const int* in_sizes, int n_in,
                              void* d_out, int out_size, void* d_ws, size_t ws_size,
                              hipStream_t stream){
    const float* x   = (const float*)d_in[0];
    const float* Wk  = (const float*)d_in[1];
    const float* bk  = (const float*)d_in[2];
    const float* Wq  = (const float*)d_in[3];
    const float* bq  = (const float*)d_in[4];
    const float* Wv  = (const float*)d_in[5];
    const float* bv  = (const float*)d_in[6];
    const float* Wr  = (const float*)d_in[7];
    const float* br  = (const float*)d_in[8];
    const float* wdw = (const float*)d_in[9];
    float* out = (float*)d_out;

    char* w = (char*)d_ws;
    ushort* S     = (ushort*)w; w += (size_t)3*BCHW*2;         // S0=xb, S1=L1, S2=L2
    ushort* xTb   = (ushort*)w; w += (size_t)BCHW*2;
    ushort* P     = (ushort*)w; w += (size_t)3*BCHW*2;         // P0,P1,P2 (live thru gram4)
    ushort* keysb = (ushort*)w; w += (size_t)BCHW*2;
    ushort* qTb   = (ushort*)w; w += (size_t)BCHW*2;
    char*   preg  = w;          w += (size_t)4*64*65536*2;     // FreH+qpreH alias / gram4 partials
    float*  att   = (float*)w;  w += (size_t)BB_*65536*4;
    float*  KX    = (float*)w;  w += (size_t)BB_*65536*4;
    ushort* Mbb   = (ushort*)w; w += (size_t)BB_*65536*2;
    ushort* Wkb   = (ushort*)w; w += 65536*2;
    ushort* Wqb   = (ushort*)w; w += 65536*2;
    float*  Wrv   = (float*)w;  w += 65536*4;
    float*  brc   = (float*)w;  w += 256*4;
    ushort* partH = (ushort*)preg;            // gram4 partials f16
    ushort* FreH  = (ushort*)preg;            // keys logits f16 (BCHW)
    ushort* qpreH = FreH + (size_t)BCHW;      // q logits f16 (BCHW)

    Taps5 T3{}, T5{};
    {
        double g[5], s;
        s = 0; for (int i = 0; i < 3; ++i){ double d = i - 1.0; g[i] = exp(-d*d/(2.0*1.6*1.6)); s += g[i]; }
        for (int i = 0; i < 3; ++i) T3.t[i] = (float)(g[i]/s);
        double sig = 1.6 * pow(2.0, 1.0/3.0);
        s = 0; for (int i = 0; i < 5; ++i){ double d = i - 2.0; g[i] = exp(-d*d/(2.0*sig*sig)); s += g[i]; }
        for (int i = 0; i < 5; ++i) T5.t[i] = (float)(g[i]/s);
    }

    const dim3 blk(256);

    // K1: prepx(2048) | plane6(2048) | prepw(160)
    prep_all<<<4256, blk, 0, stream>>>(x, Wk, Wq, Wr, Wv, bv, br,
                                       S, xTb, P, S + (size_t)BCHW, S + (size_t)2*BCHW,
                                       Wkb, Wqb, brc, Wrv, T3, T5);

    // K2: keys GEMM (512) + qpre GEMM (512) — uniform-resource body
    kq2_kernel<<<1024, blk, 0, stream>>>(Wkb, xTb, Wqb, bk, bq, FreH, qpreH);

    // K3: keys rowsm (2048) + q softmax-256 (2048)
    sm2_kernel<<<4096, blk, 0, stream>>>(FreH, qpreH, keysb, qTb);

    // K4: 4 grams in one launch (chan-att x3 + KX), 1024 blocks XCD-swizzled
    gram4_kernel<<<1024, blk, 0, stream>>>(P, keysb, S, partH);

    // K5: att softmax-accumulate (bid<2048) + KX reduce (bid>=2048)
    rsaR_kernel<<<4096, blk, 0, stream>>>(partH, att, KX);

    // K6: Mbb[b,m,k] = bf16( wdw0[m]*(Wrv@KX^T) + wdw1[m]*att[b,k,m] )
    nt256_kernel<0,1,1><<<dim3(4,4,8), blk, 0, stream>>>(Wrv, KX, nullptr, att, wdw, Mbb);

    // K7: out = Mbb @ qT^T + wdw0*(br + Wr@bv)
    mfma_nt<3,1,0><<<512, blk, 0, stream>>>(Mbb, 65536, 256, qTb, CHW, 256,
                                            out, CHW, 4096, 256, 32, 2, brc, wdw);
}

// Round 17
// 138.336 us; speedup vs baseline: 1.0633x; 1.0395x over previous
//
#include <hip/hip_runtime.h>
#include <math.h>

#define BB_ 8
#define CC_ 256
#define HWSZ 4096            // 64*64
#define CHW (CC_*HWSZ)       // 1,048,576
#define BCHW (BB_*CHW)       // 8,388,608

typedef __attribute__((ext_vector_type(8))) short short8v;
typedef __attribute__((ext_vector_type(4))) float f32x4;

struct Taps5 { float t[5]; };

__device__ inline ushort f2b(float f){
    uint u = __float_as_uint(f);
    u += 0x7FFF + ((u >> 16) & 1);
    return (ushort)(u >> 16);
}
__device__ inline float b2f(ushort u){
    return __uint_as_float(((uint)u) << 16);
}
__device__ inline ushort f2h(float f){
    _Float16 h = (_Float16)f; ushort u; __builtin_memcpy(&u, &h, 2); return u;
}
__device__ inline float h2f(ushort u){
    _Float16 h; __builtin_memcpy(&h, &u, 2); return (float)h;
}
// fast exp: exp(x) = 2^(x*log2e) via native v_exp_f32
__device__ __forceinline__ float fexp(float x){
    return __builtin_amdgcn_exp2f(x * 1.44269504088896340736f);
}
// async 16B global -> LDS (linear dest = wave-uniform base + lane*16)
__device__ __forceinline__ void gload16(const ushort* g, ushort* l){
    __builtin_amdgcn_global_load_lds(
        (const __attribute__((address_space(1))) void*)g,
        (__attribute__((address_space(3))) void*)l, 16, 0, 0);
}

// ================= K1: mega prep (prepx 2048 | plane6 2048 | prepw 160) =================
__global__ __launch_bounds__(256) void prep_all(const float* __restrict__ x,
        const float* __restrict__ Wk, const float* __restrict__ Wq,
        const float* __restrict__ Wr, const float* __restrict__ Wv,
        const float* __restrict__ bv, const float* __restrict__ br,
        ushort* __restrict__ xb, ushort* __restrict__ xTb,
        ushort* __restrict__ P, ushort* __restrict__ S1, ushort* __restrict__ S2,
        ushort* __restrict__ Wkb, ushort* __restrict__ Wqb,
        float* __restrict__ brc, float* __restrict__ Wrv,
        Taps5 t3, Taps5 t5){
    __shared__ float smem[64*65];
    const int bid = blockIdx.x;
    const int tid = threadIdx.x;

    if (bid < 2048){
        // ---- prepx role ----
        const int b = bid >> 8, c0 = ((bid >> 6) & 3)*64, h0 = (bid & 63)*64;
        const float* xp = x + (size_t)b*CHW;
        float (*T)[65] = (float(*)[65])smem;
        const int cl = tid >> 4;
        const int hl = (tid & 15) * 4;
        #pragma unroll
        for (int p = 0; p < 4; ++p){
            int c = c0 + p*16 + cl;
            float4 v = *(const float4*)&xp[(size_t)c*4096 + h0 + hl];
            ushort4 u; u.x = f2b(v.x); u.y = f2b(v.y); u.z = f2b(v.z); u.w = f2b(v.w);
            *(ushort4*)&xb[(size_t)b*CHW + (size_t)c*4096 + h0 + hl] = u;
            T[p*16+cl][hl+0] = v.x;
            T[p*16+cl][hl+1] = v.y;
            T[p*16+cl][hl+2] = v.z;
            T[p*16+cl][hl+3] = v.w;
        }
        __syncthreads();
        const int hr = tid >> 2;
        const int cs = (tid & 3) * 16;
        short8v o0, o1;
        #pragma unroll
        for (int i = 0; i < 8; ++i) o0[i] = (short)f2b(T[cs+i][hr]);
        #pragma unroll
        for (int i = 0; i < 8; ++i) o1[i] = (short)f2b(T[cs+8+i][hr]);
        ushort* dst = xTb + (size_t)b*CHW + (size_t)(h0+hr)*256 + c0 + cs;
        *(short8v*)dst = o0;
        *(short8v*)(dst+8) = o1;
        return;
    }
    if (bid < 4096){
        // ---- plane6 role ----
        const size_t base = (size_t)(bid - 2048) * HWSZ;
        const int c = tid & 63, rb = tid >> 6;
        float* bndA = smem;
        float* bndB = smem + 512;
        float* red  = smem + 1536;
        float v[16];
        #pragma unroll
        for (int i = 0; i < 16; ++i) v[i] = x[base + (rb*16 + i)*64 + c];
        float h3[16];
        #pragma unroll
        for (int i = 0; i < 16; ++i){
            float l = __shfl(v[i], c-1, 64); l = (c > 0)  ? l : 0.f;
            float r = __shfl(v[i], c+1, 64); r = (c < 63) ? r : 0.f;
            h3[i] = t3.t[0]*l + t3.t[1]*v[i] + t3.t[2]*r;
        }
        bndA[(rb*2+0)*64 + c] = h3[0]; bndA[(rb*2+1)*64 + c] = h3[15];
        __syncthreads();
        const float upA = (rb > 0) ? bndA[((rb-1)*2+1)*64 + c] : 0.f;
        const float dnA = (rb < 3) ? bndA[((rb+1)*2+0)*64 + c] : 0.f;
        float g1[16];
        #pragma unroll
        for (int i = 0; i < 16; ++i){
            float a = (i > 0)  ? h3[i-1] : upA;
            float b = (i < 15) ? h3[i+1] : dnA;
            g1[i] = t3.t[0]*a + t3.t[1]*h3[i] + t3.t[2]*b;
        }
        #pragma unroll
        for (int i = 0; i < 16; ++i){
            float m2 = __shfl(g1[i], c-2, 64); m2 = (c > 1)  ? m2 : 0.f;
            float m1 = __shfl(g1[i], c-1, 64); m1 = (c > 0)  ? m1 : 0.f;
            float p1 = __shfl(g1[i], c+1, 64); p1 = (c < 63) ? p1 : 0.f;
            float p2 = __shfl(g1[i], c+2, 64); p2 = (c < 62) ? p2 : 0.f;
            h3[i] = t5.t[0]*m2 + t5.t[1]*m1 + t5.t[2]*g1[i] + t5.t[3]*p1 + t5.t[4]*p2;
        }
        bndB[(rb*4+0)*64 + c] = h3[0];  bndB[(rb*4+1)*64 + c] = h3[1];
        bndB[(rb*4+2)*64 + c] = h3[14]; bndB[(rb*4+3)*64 + c] = h3[15];
        __syncthreads();
        const float u2 = (rb > 0) ? bndB[((rb-1)*4+2)*64 + c] : 0.f;
        const float u1 = (rb > 0) ? bndB[((rb-1)*4+3)*64 + c] : 0.f;
        const float d1 = (rb < 3) ? bndB[((rb+1)*4+0)*64 + c] : 0.f;
        const float d2 = (rb < 3) ? bndB[((rb+1)*4+1)*64 + c] : 0.f;
        float g2[16];
        #pragma unroll
        for (int i = 0; i < 16; ++i){
            float a = (i >= 2) ? h3[i-2] : (i == 1 ? u1 : u2);
            float b = (i >= 1) ? h3[i-1] : u1;
            float d = (i < 15) ? h3[i+1] : d1;
            float e = (i < 14) ? h3[i+2] : (i == 14 ? d1 : d2);
            g2[i] = t5.t[0]*a + t5.t[1]*b + t5.t[2]*h3[i] + t5.t[3]*d + t5.t[4]*e;
        }
        const size_t orow = base + (size_t)rb*16*64 + c;
        #pragma unroll
        for (int i = 0; i < 16; ++i){
            S1[orow + i*64] = f2b(v[i] - g1[i]);
            S2[orow + i*64] = f2b(g1[i] - g2[i]);
        }
        const int wid = tid >> 6, lane = tid & 63;
        #pragma unroll
        for (int g = 0; g < 3; ++g){
            float val[16];
            #pragma unroll
            for (int i = 0; i < 16; ++i)
                val[i] = (g == 0) ? v[i] : (g == 1 ? v[i] - g1[i] : g1[i] - g2[i]);
            float mx = val[0];
            #pragma unroll
            for (int i = 1; i < 16; ++i) mx = fmaxf(mx, val[i]);
            #pragma unroll
            for (int off = 32; off > 0; off >>= 1) mx = fmaxf(mx, __shfl_xor(mx, off));
            if (lane == 0) red[g*8 + wid] = mx;
            __syncthreads();
            mx = fmaxf(fmaxf(red[g*8+0], red[g*8+1]), fmaxf(red[g*8+2], red[g*8+3]));
            float s = 0.f;
            #pragma unroll
            for (int i = 0; i < 16; ++i){ val[i] = fexp(val[i] - mx); s += val[i]; }
            #pragma unroll
            for (int off = 32; off > 0; off >>= 1) s += __shfl_xor(s, off);
            if (lane == 0) red[g*8 + 4 + wid] = s;
            __syncthreads();
            s = red[g*8+4] + red[g*8+5] + red[g*8+6] + red[g*8+7];
            float inv = 1.f / s;
            ushort* Pg = P + (size_t)g*BCHW;
            #pragma unroll
            for (int i = 0; i < 16; ++i) Pg[orow + i*64] = f2b(val[i]*inv);
        }
        return;
    }
    // ---- prepw role ----
    const int blk = bid - 4096;
    if (blk < 128){
        const float* src = (blk < 64) ? Wk : Wq;
        ushort* dst = (blk < 64) ? Wkb : Wqb;
        int i = (blk & 63)*256 + tid;
        float4 v = *(const float4*)&src[i*4];
        ushort4 u; u.x = f2b(v.x); u.y = f2b(v.y); u.z = f2b(v.z); u.w = f2b(v.w);
        *(ushort4*)&dst[i*4] = u;
        return;
    }
    if (blk < 144){
        int m = (blk - 128)*16 + (tid >> 4);
        int l16 = tid & 15;
        float s = 0.f;
        #pragma unroll
        for (int t = 0; t < 4; ++t){
            float4 a = *(const float4*)&Wr[(size_t)m*256 + l16*16 + t*4];
            float4 b = *(const float4*)&bv[l16*16 + t*4];
            s += a.x*b.x + a.y*b.y + a.z*b.z + a.w*b.w;
        }
        #pragma unroll
        for (int off = 1; off < 16; off <<= 1) s += __shfl_xor(s, off);
        if (l16 == 0) brc[m] = br[m] + s;
        return;
    }
    {
        const int t = blk - 144;
        const int m0 = (t >> 2) * 64, n0 = (t & 3) * 64;
        float* As = smem;
        float* Bs = smem + 2112;
        const int tx = tid & 15, ty = tid >> 4;
        float acc[4][4] = {};
        for (int k0 = 0; k0 < 256; k0 += 32){
            int kk = tid & 31, ml = tid >> 5;
            #pragma unroll
            for (int r = 0; r < 8; ++r){
                int m = ml + r*8;
                As[kk*66 + m] = Wr[(size_t)(m0+m)*256 + k0 + kk];
            }
            int j = tid & 63, kg = tid >> 6;
            #pragma unroll
            for (int r = 0; r < 8; ++r){
                int kk2 = kg + r*4;
                Bs[kk2*64 + j] = Wv[(size_t)(k0+kk2)*256 + n0 + j];
            }
            __syncthreads();
            #pragma unroll
            for (int kk2 = 0; kk2 < 32; ++kk2){
                float4 bv4 = *(const float4*)&Bs[kk2*64 + tx*4];
                float av[4] = {As[kk2*66+ty*4+0], As[kk2*66+ty*4+1], As[kk2*66+ty*4+2], As[kk2*66+ty*4+3]};
                float bw[4] = {bv4.x, bv4.y, bv4.z, bv4.w};
                #pragma unroll
                for (int i = 0; i < 4; ++i)
                    #pragma unroll
                    for (int j2 = 0; j2 < 4; ++j2)
                        acc[i][j2] += av[i]*bw[j2];
            }
            __syncthreads();
        }
        #pragma unroll
        for (int i = 0; i < 4; ++i){
            float4 wv4 = {acc[i][0], acc[i][1], acc[i][2], acc[i][3]};
            *(float4*)&Wrv[(size_t)(m0+ty*4+i)*256 + n0 + tx*4] = wv4;
        }
    }
}

// ================= K2: kq2 — keys GEMM (512) + qpre GEMM (512), uniform body =================
__global__ __launch_bounds__(256) void kq2_kernel(const ushort* __restrict__ Wkb,
        const ushort* __restrict__ xTb, const ushort* __restrict__ Wqb,
        const float* __restrict__ bk, const float* __restrict__ bq,
        ushort* __restrict__ FreH, ushort* __restrict__ qpreH){
    __shared__ ushort As[128*64];
    __shared__ ushort Bs[128*64];
    const int bid = blockIdx.x;
    const int vid = (bid & 7)*128 + (bid >> 3);   // 1024 blocks, bijective
    const int tid = threadIdx.x;
    const int l = tid & 63, w = tid >> 6;
    const int wm = (w >> 1) * 64, wn = (w & 1) * 64;
    const int lr8 = l >> 3;
    const int lk = ((l & 7) ^ lr8) << 3;
    const bool keys = (vid < 512);
    const int sub = keys ? vid : vid - 512;
    const int b = sub >> 6;
    const int t = sub & 63;
    const int m0 = keys ? (t & 1)*128 : (t >> 1)*128;
    const int n0 = keys ? (t >> 1)*128 : (t & 1)*128;
    const ushort* Ag = keys
        ? Wkb + (size_t)(m0 + w*32 + lr8)*256 + lk
        : xTb + (size_t)b*CHW + (size_t)(m0 + w*32 + lr8)*256 + lk;
    const ushort* Bg = keys
        ? xTb + (size_t)b*CHW + (size_t)(n0 + w*32 + lr8)*256 + lk
        : Wqb + (size_t)(n0 + w*32 + lr8)*256 + lk;
    int rabase[4], raswz[4], rbbase[4], rbswz[4];
    #pragma unroll
    for (int f = 0; f < 4; ++f){
        int ra = wm + f*16 + (l & 15);
        int rb = wn + f*16 + (l & 15);
        rabase[f] = ra*64 + (l>>4)*8;  raswz[f] = (ra & 7) << 3;
        rbbase[f] = rb*64 + (l>>4)*8;  rbswz[f] = (rb & 7) << 3;
    }
    f32x4 acc[4][4] = {};
    for (int kt = 0; kt < 4; ++kt){
        #pragma unroll
        for (int i = 0; i < 4; ++i){
            gload16(Ag + (size_t)i*8*256 + kt*64, &As[(w*32 + i*8)*64]);
            gload16(Bg + (size_t)i*8*256 + kt*64, &Bs[(w*32 + i*8)*64]);
        }
        __syncthreads();
        #pragma unroll
        for (int ks = 0; ks < 2; ++ks){
            short8v af[4], bf[4];
            #pragma unroll
            for (int f = 0; f < 4; ++f){
                af[f] = *(const short8v*)&As[(rabase[f] + ks*32) ^ raswz[f]];
                bf[f] = *(const short8v*)&Bs[(rbbase[f] + ks*32) ^ rbswz[f]];
            }
            #pragma unroll
            for (int fi = 0; fi < 4; ++fi)
                #pragma unroll
                for (int fj = 0; fj < 4; ++fj)
                    acc[fi][fj] = __builtin_amdgcn_mfma_f32_16x16x32_bf16(af[fi], bf[fj], acc[fi][fj], 0, 0, 0);
        }
        __syncthreads();
    }
    const int erow = (l >> 4) * 4, ecol = l & 15;
    if (keys){
        #pragma unroll
        for (int fi = 0; fi < 4; ++fi){
            #pragma unroll
            for (int r = 0; r < 4; ++r){
                const int m = m0 + wm + fi*16 + erow + r;
                const float madd = bk[m];
                #pragma unroll
                for (int fj = 0; fj < 4; ++fj){
                    const int n = n0 + wn + fj*16 + ecol;
                    FreH[(size_t)b*CHW + (size_t)m*4096 + n] = f2h(acc[fi][fj][r] + madd);
                }
            }
        }
    } else {
        #pragma unroll
        for (int fi = 0; fi < 4; ++fi){
            #pragma unroll
            for (int r = 0; r < 4; ++r){
                const int m = m0 + wm + fi*16 + erow + r;
                #pragma unroll
                for (int fj = 0; fj < 4; ++fj){
                    const int n = n0 + wn + fj*16 + ecol;
                    qpreH[(size_t)b*CHW + (size_t)m*256 + n] = f2h(acc[fi][fj][r] + bq[n]);
                }
            }
        }
    }
}

// ================= K3: sm2 — keys rowsm over 4096 (bid<2048) + q softmax over 256 =================
__global__ __launch_bounds__(256) void sm2_kernel(const ushort* __restrict__ FreH,
        const ushort* __restrict__ qpreH,
        ushort* __restrict__ keysb, ushort* __restrict__ qTb){
    const int bid = blockIdx.x;
    const int tid = threadIdx.x;
    if (bid < 2048){
        const size_t base = (size_t)bid * HWSZ + tid * 16;
        float v[16];
        {
            short8v a = *(const short8v*)(FreH + base);
            short8v b = *(const short8v*)(FreH + base + 8);
            #pragma unroll
            for (int i = 0; i < 8; ++i){ v[i] = h2f((ushort)a[i]); v[8+i] = h2f((ushort)b[i]); }
        }
        float m = v[0];
        #pragma unroll
        for (int i = 1; i < 16; ++i) m = fmaxf(m, v[i]);
        #pragma unroll
        for (int off = 32; off > 0; off >>= 1) m = fmaxf(m, __shfl_xor(m, off));
        __shared__ float redm[4], reds[4];
        int wid = tid >> 6, lane = tid & 63;
        if (lane == 0) redm[wid] = m;
        __syncthreads();
        m = fmaxf(fmaxf(redm[0], redm[1]), fmaxf(redm[2], redm[3]));
        float s = 0.f;
        #pragma unroll
        for (int i = 0; i < 16; ++i){ v[i] = fexp(v[i] - m); s += v[i]; }
        #pragma unroll
        for (int off = 32; off > 0; off >>= 1) s += __shfl_xor(s, off);
        if (lane == 0) reds[wid] = s;
        __syncthreads();
        s = reds[0] + reds[1] + reds[2] + reds[3];
        float inv = 1.f / s;
        short8v o0, o1;
        #pragma unroll
        for (int i = 0; i < 8; ++i){ o0[i] = (short)f2b(v[i]*inv); o1[i] = (short)f2b(v[8+i]*inv); }
        ushort* op = keysb + base;
        *(short8v*)op = o0; *(short8v*)(op+8) = o1;
    } else {
        const int q = bid - 2048;
        const size_t row = (size_t)q*16 + (tid >> 4);
        const int l16 = tid & 15;
        const size_t base = row*256 + l16*16;
        float v[16];
        {
            short8v a = *(const short8v*)(qpreH + base);
            short8v b = *(const short8v*)(qpreH + base + 8);
            #pragma unroll
            for (int i = 0; i < 8; ++i){ v[i] = h2f((ushort)a[i]); v[8+i] = h2f((ushort)b[i]); }
        }
        float m = v[0];
        #pragma unroll
        for (int i = 1; i < 16; ++i) m = fmaxf(m, v[i]);
        #pragma unroll
        for (int off = 1; off < 16; off <<= 1) m = fmaxf(m, __shfl_xor(m, off));
        float s = 0.f;
        #pragma unroll
        for (int i = 0; i < 16; ++i){ v[i] = fexp(v[i] - m); s += v[i]; }
        #pragma unroll
        for (int off = 1; off < 16; off <<= 1) s += __shfl_xor(s, off);
        float inv = 1.f / s;
        short8v o0, o1;
        #pragma unroll
        for (int i = 0; i < 8; ++i){ o0[i] = (short)f2b(v[i]*inv); o1[i] = (short)f2b(v[8+i]*inv); }
        *(short8v*)(qTb + base) = o0;
        *(short8v*)(qTb + base + 8) = o1;
    }
}

// ---------------- gram4: 4 grams, split-K 4 (K-chunk 1024), 512 blocks XCD-swizzled ----------------
// z = g*32 + bb*4 + kc (128 z, 4 tiles each). f16 partials at z*65536.
__global__ __launch_bounds__(256) void gram4_kernel(
        const ushort* __restrict__ P, const ushort* __restrict__ keysb,
        const ushort* __restrict__ S, ushort* __restrict__ part){
    __shared__ ushort As[128*64];
    __shared__ ushort Bs[128*64];
    const int bid = blockIdx.x;
    const int vid = (bid & 7) * (gridDim.x >> 3) + (bid >> 3);
    const int z = vid >> 2;          // 0..127
    const int t = vid & 3;
    const int m0 = (t & 1) * 128, n0 = (t >> 1) * 128;
    const int g = z >> 5;            // 0..3
    const int bb = (z >> 2) & 7;
    const int kc = z & 3;
    const int kbeg = kc * 1024;
    const ushort* Abase = (g < 3) ? P + (size_t)g*BCHW : keysb;
    const ushort* Bbase = S + (size_t)((g == 3) ? 0 : g)*BCHW;
    const int tid = threadIdx.x;
    const int l = tid & 63, w = tid >> 6;
    const int wm = (w >> 1) * 64, wn = (w & 1) * 64;
    const int lr8 = l >> 3;
    const int lk = ((l & 7) ^ lr8) << 3;
    const ushort* Ag = Abase + (size_t)bb*CHW + (size_t)(m0 + w*32 + lr8)*4096 + kbeg + lk;
    const ushort* Bg = Bbase + (size_t)bb*CHW + (size_t)(n0 + w*32 + lr8)*4096 + kbeg + lk;
    int rabase[4], raswz[4], rbbase[4], rbswz[4];
    #pragma unroll
    for (int f = 0; f < 4; ++f){
        int ra = wm + f*16 + (l & 15);
        int rb = wn + f*16 + (l & 15);
        rabase[f] = ra*64 + (l>>4)*8;  raswz[f] = (ra & 7) << 3;
        rbbase[f] = rb*64 + (l>>4)*8;  rbswz[f] = (rb & 7) << 3;
    }
    f32x4 acc[4][4] = {};
    for (int kt = 0; kt < 16; ++kt){
        #pragma unroll
        for (int i = 0; i < 4; ++i){
            gload16(Ag + (size_t)i*8*4096 + kt*64, &As[(w*32 + i*8)*64]);
            gload16(Bg + (size_t)i*8*4096 + kt*64, &Bs[(w*32 + i*8)*64]);
        }
        __syncthreads();
        #pragma unroll
        for (int ks = 0; ks < 2; ++ks){
            short8v af[4], bf[4];
            #pragma unroll
            for (int f = 0; f < 4; ++f){
                af[f] = *(const short8v*)&As[(rabase[f] + ks*32) ^ raswz[f]];
                bf[f] = *(const short8v*)&Bs[(rbbase[f] + ks*32) ^ rbswz[f]];
            }
            #pragma unroll
            for (int fi = 0; fi < 4; ++fi)
                #pragma unroll
                for (int fj = 0; fj < 4; ++fj)
                    acc[fi][fj] = __builtin_amdgcn_mfma_f32_16x16x32_bf16(af[fi], bf[fj], acc[fi][fj], 0, 0, 0);
        }
        __syncthreads();
    }
    const int erow = (l >> 4) * 4, ecol = l & 15;
    #pragma unroll
    for (int fi = 0; fi < 4; ++fi){
        #pragma unroll
        for (int r = 0; r < 4; ++r){
            const int m = m0 + wm + fi*16 + erow + r;
            #pragma unroll
            for (int fj = 0; fj < 4; ++fj){
                const int n = n0 + wn + fj*16 + ecol;
                part[((size_t)z << 16) + (size_t)m*256 + n] = f2h(acc[fi][fj][r]);
            }
        }
    }
}

// ---------------- merged: rsa3 (bid<2048) + KX reduce (bid>=2048), 4 partials ----------------
__global__ __launch_bounds__(256) void rsaR_kernel(const ushort* __restrict__ part,
                                                   float* __restrict__ att,
                                                   float* __restrict__ KX){
    const int bid = blockIdx.x;
    const int tid = threadIdx.x;
    if (bid < 2048){
        const int row = bid;
        const int b = row >> 8;
        const int wid = tid >> 6, lane = tid & 63;
        __shared__ float redm[3][4], reds[3][4];
        float r[3];
        #pragma unroll
        for (int g = 0; g < 3; ++g){
            const size_t base = (((size_t)(g*32 + b*4)) << 16) + (size_t)(row & 255)*256 + tid;
            float v = 0.f;
            #pragma unroll
            for (int kc = 0; kc < 4; ++kc) v += h2f(part[base + ((size_t)kc << 16)]);
            float m = v;
            #pragma unroll
            for (int off = 32; off > 0; off >>= 1) m = fmaxf(m, __shfl_xor(m, off));
            if (lane == 0) redm[g][wid] = m;
            __syncthreads();
            m = fmaxf(fmaxf(redm[g][0], redm[g][1]), fmaxf(redm[g][2], redm[g][3]));
            float e = fexp(v - m);
            float s = e;
            #pragma unroll
            for (int off = 32; off > 0; off >>= 1) s += __shfl_xor(s, off);
            if (lane == 0) reds[g][wid] = s;
            __syncthreads();
            s = reds[g][0] + reds[g][1] + reds[g][2] + reds[g][3];
            r[g] = e / s;
        }
        att[(size_t)row*256 + tid] = r[0] + r[1] + r[2];
    } else {
        int i = (bid - 2048)*256 + tid;
        int b = i >> 16; int r = i & 65535;
        float s = 0.f;
        #pragma unroll
        for (int kc = 0; kc < 4; ++kc)
            s += h2f(part[(((size_t)(96 + b*4 + kc)) << 16) + r]);
        KX[i] = s;
    }
}

// ---------------- small NT gemm 256x256x256 per-batch (f32 VALU) ----------------
template<int ABATCH, int BBATCH, int EPI>
__global__ __launch_bounds__(256) void nt256_kernel(const float* __restrict__ A,
        const float* __restrict__ B, const float* __restrict__ bias,
        const float* __restrict__ att, const float* __restrict__ wdw,
        void* __restrict__ Cout){
    const int bb = blockIdx.z;
    const int m0 = blockIdx.y * 64, n0 = blockIdx.x * 64;
    const float* Ab = ABATCH ? A + (size_t)bb*65536 : A;
    const float* Bb = BBATCH ? B + (size_t)bb*65536 : B;
    __shared__ float Au[32*68];
    __shared__ float Bu[32*68];
    const int tid = threadIdx.x;
    const int tx = tid & 15, ty = tid >> 4;
    const int row = tid >> 2, loff = (tid & 3) * 8;
    float acc[4][4] = {};
    for (int k0 = 0; k0 < 256; k0 += 32){
        float4 a0 = *(const float4*)&Ab[(size_t)(m0+row)*256 + k0 + loff];
        float4 a1 = *(const float4*)&Ab[(size_t)(m0+row)*256 + k0 + loff + 4];
        float4 b0 = *(const float4*)&Bb[(size_t)(n0+row)*256 + k0 + loff];
        float4 b1 = *(const float4*)&Bb[(size_t)(n0+row)*256 + k0 + loff + 4];
        Au[(loff+0)*68 + row] = a0.x;
        Au[(loff+1)*68 + row] = a0.y;
        Au[(loff+2)*68 + row] = a0.z;
        Au[(loff+3)*68 + row] = a0.w;
        Au[(loff+4)*68 + row] = a1.x;
        Au[(loff+5)*68 + row] = a1.y;
        Au[(loff+6)*68 + row] = a1.z;
        Au[(loff+7)*68 + row] = a1.w;
        Bu[(loff+0)*68 + row] = b0.x;
        Bu[(loff+1)*68 + row] = b0.y;
        Bu[(loff+2)*68 + row] = b0.z;
        Bu[(loff+3)*68 + row] = b0.w;
        Bu[(loff+4)*68 + row] = b1.x;
        Bu[(loff+5)*68 + row] = b1.y;
        Bu[(loff+6)*68 + row] = b1.z;
        Bu[(loff+7)*68 + row] = b1.w;
        __syncthreads();
        #pragma unroll
        for (int kk = 0; kk < 32; ++kk){
            float4 av = *(const float4*)&Au[kk*68 + ty*4];
            float4 bv = *(const float4*)&Bu[kk*68 + tx*4];
            float aa[4] = {av.x, av.y, av.z, av.w};
            float bb2[4] = {bv.x, bv.y, bv.z, bv.w};
            #pragma unroll
            for (int i = 0; i < 4; ++i)
                #pragma unroll
                for (int j = 0; j < 4; ++j)
                    acc[i][j] += aa[i]*bb2[j];
        }
        __syncthreads();
    }
    #pragma unroll
    for (int i = 0; i < 4; ++i){
        int m = m0 + ty*4 + i;
        ushort4 uv;
        ushort* up = &uv.x;
        #pragma unroll
        for (int j = 0; j < 4; ++j){
            int n = n0 + tx*4 + j;
            float v = wdw[2*m]*acc[i][j] + wdw[2*m+1]*att[(size_t)bb*65536 + (size_t)n*256 + m];
            up[j] = f2b(v);
        }
        *(ushort4*)&((ushort*)Cout)[(size_t)bb*65536 + (size_t)m*256 + n0 + tx*4] = uv;
    }
}

// ---------------- MFMA NT GEMM (generic, for final out) ----------------
template<int EPI, int KC, int POUT>
__global__ __launch_bounds__(256) void mfma_nt(
        const ushort* __restrict__ A, size_t Abstride, int lda,
        const ushort* __restrict__ B, size_t Bbstride, int ldb,
        void* __restrict__ C, size_t Czstride, int ldc,
        int Kchunk, int ntx, int nty,
        const float* __restrict__ bias, const float* __restrict__ wdw){
    __shared__ ushort As[128*64];
    __shared__ ushort Bs[128*64];
    const int bid = blockIdx.x;
    const int vid = (bid & 7) * (gridDim.x >> 3) + (bid >> 3);
    const int nt = ntx * nty;
    const int z = vid / nt;
    const int t = vid - z * nt;
    const int m0 = (t % nty) * 128, n0 = (t / nty) * 128;
    const int bb = z / KC;
    const int kc = z - bb * KC;
    const int kbeg = kc * Kchunk;
    const int tid = threadIdx.x;
    const int l = tid & 63, w = tid >> 6;
    const int wm = (w >> 1) * 64, wn = (w & 1) * 64;
    const int lr8 = l >> 3;
    const int lk = ((l & 7) ^ lr8) << 3;
    const ushort* Ag = A + (size_t)bb*Abstride + (size_t)(m0 + w*32 + lr8)*lda + kbeg + lk;
    const ushort* Bg = B + (size_t)bb*Bbstride + (size_t)(n0 + w*32 + lr8)*ldb + kbeg + lk;
    int rabase[4], raswz[4], rbbase[4], rbswz[4];
    #pragma unroll
    for (int f = 0; f < 4; ++f){
        int ra = wm + f*16 + (l & 15);
        int rb = wn + f*16 + (l & 15);
        rabase[f] = ra*64 + (l>>4)*8;  raswz[f] = (ra & 7) << 3;
        rbbase[f] = rb*64 + (l>>4)*8;  rbswz[f] = (rb & 7) << 3;
    }
    f32x4 acc[4][4] = {};
    const int ktiles = Kchunk >> 6;
    for (int kt = 0; kt < ktiles; ++kt){
        #pragma unroll
        for (int i = 0; i < 4; ++i){
            gload16(Ag + (size_t)i*8*lda + kt*64, &As[(w*32 + i*8)*64]);
            gload16(Bg + (size_t)i*8*ldb + kt*64, &Bs[(w*32 + i*8)*64]);
        }
        __syncthreads();
        #pragma unroll
        for (int ks = 0; ks < 2; ++ks){
            short8v af[4], bf[4];
            #pragma unroll
            for (int f = 0; f < 4; ++f){
                af[f] = *(const short8v*)&As[(rabase[f] + ks*32) ^ raswz[f]];
                bf[f] = *(const short8v*)&Bs[(rbbase[f] + ks*32) ^ rbswz[f]];
            }
            #pragma unroll
            for (int fi = 0; fi < 4; ++fi)
                #pragma unroll
                for (int fj = 0; fj < 4; ++fj)
                    acc[fi][fj] = __builtin_amdgcn_mfma_f32_16x16x32_bf16(af[fi], bf[fj], acc[fi][fj], 0, 0, 0);
        }
        __syncthreads();
    }
    const int erow = (l >> 4) * 4, ecol = l & 15;
    #pragma unroll
    for (int fi = 0; fi < 4; ++fi){
        #pragma unroll
        for (int r = 0; r < 4; ++r){
            const int m = m0 + wm + fi*16 + erow + r;
            float madd = 0.f;
            if (EPI == 1) madd = bias[m];
            else if (EPI == 3) madd = wdw[2*m]*bias[m];
            #pragma unroll
            for (int fj = 0; fj < 4; ++fj){
                const int n = n0 + wn + fj*16 + ecol;
                float v = acc[fi][fj][r];
                if (EPI == 1 || EPI == 3) v += madd;
                size_t idx = (size_t)z*Czstride + (size_t)m*ldc + n;
                if (POUT == 0) ((float*)C)[idx] = v;
                else           ((ushort*)C)[idx] = f2h(v);
            }
        }
    }
}

// ---------------- host ----------------
extern "C" void kernel_launch(void* const* d_in, const int* in_sizes, int n_in,
                              void* d_out, int out_size, void* d_ws, size_t ws_size,
                              hipStream_t stream){
    const float* x   = (const float*)d_in[0];
    const float* Wk  = (const float*)d_in[1];
    const float* bk  = (const float*)d_in[2];
    const float* Wq  = (const float*)d_in[3];
    const float* bq  = (const float*)d_in[4];
    const float* Wv  = (const float*)d_in[5];
    const float* bv  = (const float*)d_in[6];
    const float* Wr  = (const float*)d_in[7];
    const float* br  = (const float*)d_in[8];
    const float* wdw = (const float*)d_in[9];
    float* out = (float*)d_out;

    char* w = (char*)d_ws;
    ushort* S     = (ushort*)w; w += (size_t)3*BCHW*2;         // S0=xb, S1=L1, S2=L2
    ushort* xTb   = (ushort*)w; w += (size_t)BCHW*2;
    ushort* P     = (ushort*)w; w += (size_t)3*BCHW*2;         // P0,P1,P2 (live thru gram4)
    ushort* keysb = (ushort*)w; w += (size_t)BCHW*2;
    ushort* qTb   = (ushort*)w; w += (size_t)BCHW*2;
    char*   preg  = w;          w += (size_t)4*64*65536*2;     // FreH+qpreH alias / gram4 partials
    float*  att   = (float*)w;  w += (size_t)BB_*65536*4;
    float*  KX    = (float*)w;  w += (size_t)BB_*65536*4;
    ushort* Mbb   = (ushort*)w; w += (size_t)BB_*65536*2;
    ushort* Wkb   = (ushort*)w; w += 65536*2;
    ushort* Wqb   = (ushort*)w; w += 65536*2;
    float*  Wrv   = (float*)w;  w += 65536*4;
    float*  brc   = (float*)w;  w += 256*4;
    ushort* partH = (ushort*)preg;            // gram4 partials f16 (128*65536 used)
    ushort* FreH  = (ushort*)preg;            // keys logits f16 (BCHW)
    ushort* qpreH = FreH + (size_t)BCHW;      // q logits f16 (BCHW)

    Taps5 T3{}, T5{};
    {
        double g[5], s;
        s = 0; for (int i = 0; i < 3; ++i){ double d = i - 1.0; g[i] = exp(-d*d/(2.0*1.6*1.6)); s += g[i]; }
        for (int i = 0; i < 3; ++i) T3.t[i] = (float)(g[i]/s);
        double sig = 1.6 * pow(2.0, 1.0/3.0);
        s = 0; for (int i = 0; i < 5; ++i){ double d = i - 2.0; g[i] = exp(-d*d/(2.0*sig*sig)); s += g[i]; }
        for (int i = 0; i < 5; ++i) T5.t[i] = (float)(g[i]/s);
    }

    const dim3 blk(256);

    // K1: prepx(2048) | plane6(2048) | prepw(160)
    prep_all<<<4256, blk, 0, stream>>>(x, Wk, Wq, Wr, Wv, bv, br,
                                       S, xTb, P, S + (size_t)BCHW, S + (size_t)2*BCHW,
                                       Wkb, Wqb, brc, Wrv, T3, T5);

    // K2: keys GEMM (512) + qpre GEMM (512) — uniform-resource body
    kq2_kernel<<<1024, blk, 0, stream>>>(Wkb, xTb, Wqb, bk, bq, FreH, qpreH);

    // K3: keys rowsm (2048) + q softmax-256 (2048)
    sm2_kernel<<<4096, blk, 0, stream>>>(FreH, qpreH, keysb, qTb);

    // K4: 4 grams (chan-att x3 + KX), split-K 4, 512 blocks XCD-swizzled
    gram4_kernel<<<512, blk, 0, stream>>>(P, keysb, S, partH);

    // K5: att softmax-accumulate (bid<2048) + KX reduce (bid>=2048)
    rsaR_kernel<<<4096, blk, 0, stream>>>(partH, att, KX);

    // K6: Mbb[b,m,k] = bf16( wdw0[m]*(Wrv@KX^T) + wdw1[m]*att[b,k,m] )
    nt256_kernel<0,1,1><<<dim3(4,4,8), blk, 0, stream>>>(Wrv, KX, nullptr, att, wdw, Mbb);

    // K7: out = Mbb @ qT^T + wdw0*(br + Wr@bv)
    mfma_nt<3,1,0><<<512, blk, 0, stream>>>(Mbb, 65536, 256, qTb, CHW, 256,
                                            out, CHW, 4096, 256, 32, 2, brc, wdw);
}